// Round 5
// baseline (504.957 us; speedup 1.0000x reference)
//
#include <hip/hip_runtime.h>
#include <math.h>

// B=8, N=1024, C=1024, H=16, hd=64, n_tasks=10, n_frq=3000
#define NFRQ 3000

typedef __bf16 bf16;
typedef __attribute__((ext_vector_type(8))) __bf16 bf16x8;
typedef __attribute__((ext_vector_type(4))) __bf16 bf16x4;
typedef __attribute__((ext_vector_type(4))) float floatx4;

__device__ __forceinline__ floatx4 mfma16(bf16x8 a, bf16x8 b, floatx4 c) {
  return __builtin_amdgcn_mfma_f32_16x16x32_bf16(a, b, c, 0, 0, 0);
}

// async global->LDS, 16B per lane, dest = base + lane*16
__device__ __forceinline__ void async_load16(const bf16* g, bf16* l) {
  __builtin_amdgcn_global_load_lds(
      (const __attribute__((address_space(1))) unsigned int*)g,
      (__attribute__((address_space(3))) unsigned int*)l, 16, 0, 0);
}

// ---------------------------------------------------------------------------
// DCT-II orthonormal matrix. Exact integer angle reduction: i*(2j+1) mod 4096.
__global__ __launch_bounds__(256) void dct_kernel(float* __restrict__ Bm,
                                                  bf16* __restrict__ Bmtb) {
  int t = blockIdx.x * 256 + threadIdx.x;  // 0..1M-1
  int i = t >> 10, j = t & 1023;
  const float cst = 0.04419417382415922f;       // sqrt(2)/32
  const float w = 1.5339807878856412e-3f;       // pi/2048
  int K1 = (i * (2 * j + 1)) & 4095;
  float v1 = (i == 0) ? 0.03125f : cst * __cosf((float)K1 * w);
  Bm[t] = v1;
  int K2 = (j * (2 * i + 1)) & 4095;            // Bm[j][i]
  float v2 = (j == 0) ? 0.03125f : cst * __cosf((float)K2 * w);
  Bmtb[t] = (__bf16)v2;
}

// ---------------------------------------------------------------------------
// U = S^T @ Bm for both coef sets (shared indices). U has 2 fp32 planes (k,v).
__global__ __launch_bounds__(256) void scatter2(const float* __restrict__ coef_k,
                                                const float* __restrict__ coef_v,
                                                const int* __restrict__ idx,
                                                const int* __restrict__ task,
                                                const float* __restrict__ Bm,
                                                float* __restrict__ U) {
  int nz = blockIdx.x;
  if (nz >= (*task + 1) * NFRQ) return;
  float vk = coef_k[nz], vv = coef_v[nz];
  int id = idx[nz];
  int r = id >> 10, c = id & 1023;
  const float* brow = Bm + ((size_t)r << 10);
  float* u0 = U + ((size_t)c << 10);
  float* u1 = u0 + (1u << 20);
  for (int jj = (int)threadIdx.x; jj < 1024; jj += 256) {
    float bv = brow[jj];
    atomicAdd(u0 + jj, vk * bv);
    atomicAdd(u1 + jj, vv * bv);
  }
}

// ---------------------------------------------------------------------------
// Ub[m][c] (bf16, m in [0,2048)) = U[plane=m>>10][c][m&1023]  (transpose+cvt)
__global__ __launch_bounds__(256) void transpose_u(const float* __restrict__ U,
                                                   bf16* __restrict__ Ub) {
  __shared__ float tile[64][65];
  int m0 = blockIdx.y * 64, c0 = blockIdx.x * 64;
  const float* src = U + ((size_t)(m0 >> 10) << 20);
  int mm0 = m0 & 1023;
  int t = threadIdx.x, r = t >> 2, cc = (t & 3) * 16;
#pragma unroll
  for (int i = 0; i < 4; ++i) {
    float4 f = *(const float4*)&src[(size_t)(c0 + r) * 1024 + mm0 + cc + i * 4];
    tile[r][cc + i * 4 + 0] = f.x; tile[r][cc + i * 4 + 1] = f.y;
    tile[r][cc + i * 4 + 2] = f.z; tile[r][cc + i * 4 + 3] = f.w;
  }
  __syncthreads();
  bf16x8 o0, o1;
#pragma unroll
  for (int i = 0; i < 8; ++i) o0[i] = (__bf16)tile[cc + i][r];
#pragma unroll
  for (int i = 0; i < 8; ++i) o1[i] = (__bf16)tile[cc + 8 + i][r];
  bf16* dst = Ub + (size_t)(m0 + r) * 1024 + c0 + cc;
  *(bf16x8*)&dst[0] = o0;
  *(bf16x8*)&dst[8] = o1;
}

// ---------------------------------------------------------------------------
// fp32 -> bf16 convert, n4 = n/4 float4 chunks
__global__ __launch_bounds__(256) void conv_bf16(const float* __restrict__ s,
                                                 bf16* __restrict__ d, int n4) {
  int i = blockIdx.x * 256 + threadIdx.x;
  if (i >= n4) return;
  float4 f = ((const float4*)s)[i];
  bf16x4 o = {(__bf16)f.x, (__bf16)f.y, (__bf16)f.z, (__bf16)f.w};
  *(bf16x4*)&d[(size_t)i * 4] = o;
}

// ---------------------------------------------------------------------------
// MFMA NT GEMM: C[m][n] = sum_k A[m][k]*B[n][k], K=1024 fixed, ldc=N.
// 128x128 block tile, 4 waves each 64x64 (4x4 of 16x16x32), BK=32, 16KB LDS.
// __launch_bounds__(256,4): force total regs <=128 (64 acc AGPR + operands)
// -> 4 waves/SIMD so co-resident blocks hide each other's barrier drains.
// Output: Cf!=null -> fp32 (+bias); else bf16 (+= addend fp32 if !=null).
// If vt!=null: tiles with col>=2048 (v band) are stored TRANSPOSED into
// vt[((b<<10)|vchan)<<10 | n] instead of Cb (fuses the V^T transpose).
__global__ __launch_bounds__(256, 4) void gemm_bf16_nt(const bf16* __restrict__ A,
                                                       const bf16* __restrict__ B,
                                                       bf16* __restrict__ Cb,
                                                       float* __restrict__ Cf,
                                                       const float* __restrict__ addend,
                                                       const float* __restrict__ bias,
                                                       bf16* __restrict__ vt,
                                                       int N) {
  __shared__ bf16 As[4][128][8];   // [kchunk][m][8]  8KB
  __shared__ bf16 Bs[4][128][8];   // 8KB
  int t = threadIdx.x, w = t >> 6, lane = t & 63;
  int q15 = lane & 15, quad = lane >> 4;
  int m0 = blockIdx.y * 128, n0 = blockIdx.x * 128;
  int wm = (w >> 1) * 64, wn = (w & 1) * 64;
  floatx4 acc[4][4];
#pragma unroll
  for (int i = 0; i < 4; ++i)
#pragma unroll
    for (int j = 0; j < 4; ++j) acc[i][j] = (floatx4){0.f, 0.f, 0.f, 0.f};

  const bf16* Ag = A + (size_t)(m0 + lane) * 1024 + w * 8;
  const bf16* Bg = B + (size_t)(n0 + lane) * 1024 + w * 8;

  for (int k0 = 0; k0 < 1024; k0 += 32) {
    __syncthreads();
    async_load16(Ag + k0,             &As[w][0][0]);
    async_load16(Ag + 64 * 1024 + k0, &As[w][64][0]);
    async_load16(Bg + k0,             &Bs[w][0][0]);
    async_load16(Bg + 64 * 1024 + k0, &Bs[w][64][0]);
    __syncthreads();
    bf16x8 af[4], bfr[4];
#pragma unroll
    for (int i = 0; i < 4; ++i) af[i]  = *(const bf16x8*)&As[quad][wm + i * 16 + q15][0];
#pragma unroll
    for (int j = 0; j < 4; ++j) bfr[j] = *(const bf16x8*)&Bs[quad][wn + j * 16 + q15][0];
#pragma unroll
    for (int i = 0; i < 4; ++i)
#pragma unroll
      for (int j = 0; j < 4; ++j) acc[i][j] = mfma16(af[i], bfr[j], acc[i][j]);
  }

  if (vt && (n0 + wn) >= 2048) {
    // v band: store transposed into Vt. acc[i][j][0..3] = 4 consecutive
    // x-rows (n dim) at fixed channel -> contiguous bf16x4 in Vt.
#pragma unroll
    for (int i = 0; i < 4; ++i) {
      int gm = m0 + wm + i * 16 + quad * 4;          // x row (4 consecutive)
      int b = gm >> 10, n = gm & 1023;
#pragma unroll
      for (int j = 0; j < 4; ++j) {
        int vchan = (n0 + wn - 2048) + j * 16 + q15; // h*64+d
        bf16x4 pk = {(__bf16)acc[i][j][0], (__bf16)acc[i][j][1],
                     (__bf16)acc[i][j][2], (__bf16)acc[i][j][3]};
        *(bf16x4*)&vt[((((size_t)b << 10) | vchan) << 10) | n] = pk;
      }
    }
    return;
  }

#pragma unroll
  for (int i = 0; i < 4; ++i)
#pragma unroll
    for (int r = 0; r < 4; ++r) {
      int gm = m0 + wm + i * 16 + quad * 4 + r;
      size_t rowo = (size_t)gm * N + n0 + wn;
#pragma unroll
      for (int j = 0; j < 4; ++j) {
        int col = j * 16 + q15;
        float v = acc[i][j][r];
        if (Cf) {
          Cf[rowo + col] = v + (bias ? bias[n0 + wn + col] : 0.f);
        } else {
          if (addend) v += addend[rowo + col];
          Cb[rowo + col] = (__bf16)v;
        }
      }
    }
}

// ---------------------------------------------------------------------------
// Flash attention, S^T formulation. Block = (b,h,128 q rows), 4 waves, each
// wave owns 32 q columns of S^T. kv-tiles of 64 keys.
__global__ __launch_bounds__(256) void attn_mfma(const bf16* __restrict__ qkvb,
                                                 const bf16* __restrict__ Vt,
                                                 bf16* __restrict__ attn_out) {
  __shared__ __align__(16) char smem[49152];
  bf16 (*Qs)[128][8] = (bf16(*)[128][8])smem;            // 16KB [dchunk][q][8]
  bf16 (*Ks)[64][8]  = (bf16(*)[64][8])(smem + 16384);   // 8KB  [dchunk][key][8]
  bf16 (*Vs)[64][8]  = (bf16(*)[64][8])(smem + 24576);   // 8KB  [keychunk][d][8]
  bf16* PsB = (bf16*)(smem + 32768);                     // 16KB [w][nt][kc][q16][8]

  int t = threadIdx.x, w = t >> 6, lane = t & 63;
  int q15 = lane & 15, quad = lane >> 4;
  int bh = blockIdx.y, b = bh >> 4, h = bh & 15;
  int q0 = blockIdx.x * 128;
  const float scale = 0.125f;

  const bf16* Qg = qkvb + (size_t)(b * 1024 + q0) * 3072 + h * 64;
  const bf16* Kg = qkvb + (size_t)(b * 1024) * 3072 + 1024 + h * 64;
  const bf16* Vg = Vt + (size_t)(bh * 64) * 1024;

#pragma unroll
  for (int cc = 0; cc < 2; ++cc) {
    int kc = w * 2 + cc;
    async_load16(Qg + (size_t)lane * 3072 + kc * 8,        &Qs[kc][0][0]);
    async_load16(Qg + (size_t)(64 + lane) * 3072 + kc * 8, &Qs[kc][64][0]);
  }

  floatx4 oacc[4][2];
  float m_i[2], l_i[2];
#pragma unroll
  for (int nt = 0; nt < 2; ++nt) {
    m_i[nt] = -INFINITY; l_i[nt] = 0.f;
#pragma unroll
    for (int mt = 0; mt < 4; ++mt) oacc[mt][nt] = (floatx4){0.f, 0.f, 0.f, 0.f};
  }

  for (int kt = 0; kt < 16; ++kt) {
    int kv0 = kt * 64;
    __syncthreads();
    const bf16* Kg2 = Kg + (size_t)(kv0 + lane) * 3072;
    const bf16* Vg2 = Vg + (size_t)lane * 1024 + kv0;
    async_load16(Kg2 + (w * 2) * 8,     &Ks[w * 2][0][0]);
    async_load16(Kg2 + (w * 2 + 1) * 8, &Ks[w * 2 + 1][0][0]);
    async_load16(Vg2 + (w * 2) * 8,     &Vs[w * 2][0][0]);
    async_load16(Vg2 + (w * 2 + 1) * 8, &Vs[w * 2 + 1][0][0]);
    __syncthreads();

    floatx4 sacc[4][2];
#pragma unroll
    for (int mt = 0; mt < 4; ++mt)
#pragma unroll
      for (int nt = 0; nt < 2; ++nt) sacc[mt][nt] = (floatx4){0.f, 0.f, 0.f, 0.f};
#pragma unroll
    for (int ks = 0; ks < 2; ++ks) {
      bf16x8 kf[4], qf[2];
#pragma unroll
      for (int mt = 0; mt < 4; ++mt)
        kf[mt] = *(const bf16x8*)&Ks[ks * 4 + quad][mt * 16 + q15][0];
#pragma unroll
      for (int nt = 0; nt < 2; ++nt)
        qf[nt] = *(const bf16x8*)&Qs[ks * 4 + quad][w * 32 + nt * 16 + q15][0];
#pragma unroll
      for (int mt = 0; mt < 4; ++mt)
#pragma unroll
        for (int nt = 0; nt < 2; ++nt) sacc[mt][nt] = mfma16(kf[mt], qf[nt], sacc[mt][nt]);
    }

#pragma unroll
    for (int nt = 0; nt < 2; ++nt) {
      float mx = -INFINITY;
#pragma unroll
      for (int mt = 0; mt < 4; ++mt)
#pragma unroll
        for (int r = 0; r < 4; ++r) mx = fmaxf(mx, sacc[mt][nt][r]);
      mx = fmaxf(mx, __shfl_xor(mx, 16));
      mx = fmaxf(mx, __shfl_xor(mx, 32));
      float mnew = fmaxf(m_i[nt], mx * scale);
      float alpha = __expf(m_i[nt] - mnew);
      float rsum = 0.f;
#pragma unroll
      for (int mt = 0; mt < 4; ++mt)
#pragma unroll
        for (int r = 0; r < 4; ++r) {
          float p = __expf(sacc[mt][nt][r] * scale - mnew);
          sacc[mt][nt][r] = p;
          rsum += p;
        }
      rsum += __shfl_xor(rsum, 16);
      rsum += __shfl_xor(rsum, 32);
      l_i[nt] = l_i[nt] * alpha + rsum;
      m_i[nt] = mnew;
#pragma unroll
      for (int mt = 0; mt < 4; ++mt)
#pragma unroll
        for (int r = 0; r < 4; ++r) oacc[mt][nt][r] *= alpha;
    }

#pragma unroll
    for (int nt = 0; nt < 2; ++nt)
#pragma unroll
      for (int mt = 0; mt < 4; ++mt) {
        bf16x4 pk = {(__bf16)sacc[mt][nt][0], (__bf16)sacc[mt][nt][1],
                     (__bf16)sacc[mt][nt][2], (__bf16)sacc[mt][nt][3]};
        int kc = mt * 2 + (quad >> 1);
        *(bf16x4*)&PsB[(size_t)(w * 2 + nt) * 1024 + kc * 128 + q15 * 8 + (quad & 1) * 4] = pk;
      }

#pragma unroll
    for (int ks = 0; ks < 2; ++ks) {
      bf16x8 vf[4], pf[2];
#pragma unroll
      for (int mt = 0; mt < 4; ++mt)
        vf[mt] = *(const bf16x8*)&Vs[ks * 4 + quad][mt * 16 + q15][0];
#pragma unroll
      for (int nt = 0; nt < 2; ++nt)
        pf[nt] = *(const bf16x8*)&PsB[(size_t)(w * 2 + nt) * 1024 + (ks * 4 + quad) * 128 + q15 * 8];
#pragma unroll
      for (int mt = 0; mt < 4; ++mt)
#pragma unroll
        for (int nt = 0; nt < 2; ++nt) oacc[mt][nt] = mfma16(vf[mt], pf[nt], oacc[mt][nt]);
    }
  }

  __syncthreads();
  bf16* T = (bf16*)smem + w * 2304;   // [32 q][72]
#pragma unroll
  for (int nt = 0; nt < 2; ++nt) {
    float inv = 1.f / l_i[nt];
#pragma unroll
    for (int mt = 0; mt < 4; ++mt) {
      bf16x4 pk = {(__bf16)(oacc[mt][nt][0] * inv), (__bf16)(oacc[mt][nt][1] * inv),
                   (__bf16)(oacc[mt][nt][2] * inv), (__bf16)(oacc[mt][nt][3] * inv)};
      *(bf16x4*)&T[(nt * 16 + q15) * 72 + mt * 16 + quad * 4] = pk;
    }
  }
  int row = lane >> 1, ch = (lane & 1) * 32;
  const bf16* Tr = T + row * 72 + ch;
  bf16* outp = attn_out + (size_t)(b * 1024 + q0 + w * 32 + row) * 1024 + h * 64 + ch;
#pragma unroll
  for (int i = 0; i < 4; ++i) *(bf16x8*)&outp[i * 8] = *(const bf16x8*)&Tr[i * 8];
}

// ---------------------------------------------------------------------------
extern "C" void kernel_launch(void* const* d_in, const int* in_sizes, int n_in,
                              void* d_out, int out_size, void* d_ws, size_t ws_size,
                              hipStream_t stream) {
  (void)in_sizes; (void)n_in; (void)out_size; (void)ws_size;
  const float* x       = (const float*)d_in[0];   // 8x1024x1024
  const float* W_qkv   = (const float*)d_in[1];   // 3072x1024
  const float* W_proj  = (const float*)d_in[2];   // 1024x1024
  const float* b_proj  = (const float*)d_in[3];   // 1024
  const float* coef_k  = (const float*)d_in[4];   // 10x3000
  const float* coef_v  = (const float*)d_in[5];   // 10x3000
  const int*   indices = (const int*)d_in[6];     // 10x3000
  const int*   task    = (const int*)d_in[7];     // scalar

  // Workspace (104 MB peak). attn_out aliases the dead Bm/U/Ub region.
  char* w8 = (char*)d_ws;
  float* Bm     = (float*)(w8);                  // 4MB
  float* U      = (float*)(w8 + (4u  << 20));    // 8MB (k,v planes)
  bf16*  Ub     = (bf16*) (w8 + (12u << 20));    // 4MB [2048][1024]
  bf16*  Bmtb   = (bf16*) (w8 + (16u << 20));    // 2MB
  bf16*  Wcb    = (bf16*) (w8 + (18u << 20));    // 6MB [3072][1024]
  bf16*  xb     = (bf16*) (w8 + (24u << 20));    // 16MB
  bf16*  qkvb   = (bf16*) (w8 + (40u << 20));    // 48MB [8192][3072]
  bf16*  Vt     = (bf16*) (w8 + (88u << 20));    // 16MB [128][64][1024]
  bf16*  attnout= (bf16*) (w8);                  // 16MB alias (Bm/U/Ub dead)

  dct_kernel<<<4096, 256, 0, stream>>>(Bm, Bmtb);

  hipMemsetAsync(U, 0, (size_t)8 << 20, stream);
  scatter2<<<10 * NFRQ, 256, 0, stream>>>(coef_k, coef_v, indices, task, Bm, U);
  transpose_u<<<dim3(16, 32), 256, 0, stream>>>(U, Ub);

  conv_bf16<<<1024, 256, 0, stream>>>(W_qkv, Wcb, 262144);
  conv_bf16<<<8192, 256, 0, stream>>>(x, xb, 2097152);

  // k,v bands: Wcb[1024+m][n] = sum_c Ub[m][c]*Bmtb[n][c] + W_qkv[1024+m][n]
  gemm_bf16_nt<<<dim3(8, 16), 256, 0, stream>>>(Ub, Bmtb, Wcb + (1u << 20), nullptr,
                                                W_qkv + (1u << 20), nullptr, nullptr, 1024);

  // W_proj -> bf16 (into Bmtb slot, dead after lora GEMM)
  bf16* Wprojb = Bmtb;
  conv_bf16<<<1024, 256, 0, stream>>>(W_proj, Wprojb, 262144);

  // qkv = xb @ Wcb^T -> q,k bands bf16 into qkvb; v band transposed into Vt
  gemm_bf16_nt<<<dim3(24, 64), 256, 0, stream>>>(xb, Wcb, qkvb, nullptr,
                                                 nullptr, nullptr, Vt, 3072);

  // attention
  attn_mfma<<<dim3(8, 128), 256, 0, stream>>>(qkvb, Vt, attnout);

  // out = attn_out @ W_proj^T + b_proj  (fp32 out)
  gemm_bf16_nt<<<dim3(8, 64), 256, 0, stream>>>(attnout, Wprojb, nullptr, (float*)d_out,
                                                nullptr, b_proj, nullptr, 1024);
}

// Round 6
// 498.299 us; speedup vs baseline: 1.0134x; 1.0134x over previous
//
#include <hip/hip_runtime.h>
#include <math.h>

// B=8, N=1024, C=1024, H=16, hd=64, n_tasks=10, n_frq=3000
#define NFRQ 3000

typedef __bf16 bf16;
typedef __attribute__((ext_vector_type(8))) __bf16 bf16x8;
typedef __attribute__((ext_vector_type(4))) __bf16 bf16x4;
typedef __attribute__((ext_vector_type(4))) float floatx4;

__device__ __forceinline__ floatx4 mfma16(bf16x8 a, bf16x8 b, floatx4 c) {
  return __builtin_amdgcn_mfma_f32_16x16x32_bf16(a, b, c, 0, 0, 0);
}

// async global->LDS, 16B per lane, dest = base + lane*16
__device__ __forceinline__ void async_load16(const bf16* g, bf16* l) {
  __builtin_amdgcn_global_load_lds(
      (const __attribute__((address_space(1))) unsigned int*)g,
      (__attribute__((address_space(3))) unsigned int*)l, 16, 0, 0);
}

// ---------------------------------------------------------------------------
// DCT-II orthonormal matrix. Exact integer angle reduction: i*(2j+1) mod 4096.
__global__ __launch_bounds__(256) void dct_kernel(float* __restrict__ Bm,
                                                  bf16* __restrict__ Bmtb) {
  int t = blockIdx.x * 256 + threadIdx.x;  // 0..1M-1
  int i = t >> 10, j = t & 1023;
  const float cst = 0.04419417382415922f;       // sqrt(2)/32
  const float w = 1.5339807878856412e-3f;       // pi/2048
  int K1 = (i * (2 * j + 1)) & 4095;
  float v1 = (i == 0) ? 0.03125f : cst * __cosf((float)K1 * w);
  Bm[t] = v1;
  int K2 = (j * (2 * i + 1)) & 4095;            // Bm[j][i]
  float v2 = (j == 0) ? 0.03125f : cst * __cosf((float)K2 * w);
  Bmtb[t] = (__bf16)v2;
}

// ---------------------------------------------------------------------------
// U = S^T @ Bm for both coef sets (shared indices). U has 2 fp32 planes (k,v).
__global__ __launch_bounds__(256) void scatter2(const float* __restrict__ coef_k,
                                                const float* __restrict__ coef_v,
                                                const int* __restrict__ idx,
                                                const int* __restrict__ task,
                                                const float* __restrict__ Bm,
                                                float* __restrict__ U) {
  int nz = blockIdx.x;
  if (nz >= (*task + 1) * NFRQ) return;
  float vk = coef_k[nz], vv = coef_v[nz];
  int id = idx[nz];
  int r = id >> 10, c = id & 1023;
  const float* brow = Bm + ((size_t)r << 10);
  float* u0 = U + ((size_t)c << 10);
  float* u1 = u0 + (1u << 20);
  for (int jj = (int)threadIdx.x; jj < 1024; jj += 256) {
    float bv = brow[jj];
    atomicAdd(u0 + jj, vk * bv);
    atomicAdd(u1 + jj, vv * bv);
  }
}

// ---------------------------------------------------------------------------
// Ub[m][c] (bf16, m in [0,2048)) = U[plane=m>>10][c][m&1023]  (transpose+cvt)
__global__ __launch_bounds__(256) void transpose_u(const float* __restrict__ U,
                                                   bf16* __restrict__ Ub) {
  __shared__ float tile[64][65];
  int m0 = blockIdx.y * 64, c0 = blockIdx.x * 64;
  const float* src = U + ((size_t)(m0 >> 10) << 20);
  int mm0 = m0 & 1023;
  int t = threadIdx.x, r = t >> 2, cc = (t & 3) * 16;
#pragma unroll
  for (int i = 0; i < 4; ++i) {
    float4 f = *(const float4*)&src[(size_t)(c0 + r) * 1024 + mm0 + cc + i * 4];
    tile[r][cc + i * 4 + 0] = f.x; tile[r][cc + i * 4 + 1] = f.y;
    tile[r][cc + i * 4 + 2] = f.z; tile[r][cc + i * 4 + 3] = f.w;
  }
  __syncthreads();
  bf16x8 o0, o1;
#pragma unroll
  for (int i = 0; i < 8; ++i) o0[i] = (__bf16)tile[cc + i][r];
#pragma unroll
  for (int i = 0; i < 8; ++i) o1[i] = (__bf16)tile[cc + 8 + i][r];
  bf16* dst = Ub + (size_t)(m0 + r) * 1024 + c0 + cc;
  *(bf16x8*)&dst[0] = o0;
  *(bf16x8*)&dst[8] = o1;
}

// ---------------------------------------------------------------------------
// fp32 -> bf16 convert, n4 = n/4 float4 chunks
__global__ __launch_bounds__(256) void conv_bf16(const float* __restrict__ s,
                                                 bf16* __restrict__ d, int n4) {
  int i = blockIdx.x * 256 + threadIdx.x;
  if (i >= n4) return;
  float4 f = ((const float4*)s)[i];
  bf16x4 o = {(__bf16)f.x, (__bf16)f.y, (__bf16)f.z, (__bf16)f.w};
  *(bf16x4*)&d[(size_t)i * 4] = o;
}

// ---------------------------------------------------------------------------
// MFMA NT GEMM: C[m][n] = sum_k A[m][k]*B[n][k], K=1024 fixed, ldc=N.
// 128x128 block tile, 4 waves each 64x64 (4x4 of 16x16x32), BK=32, 16KB LDS.
// XCD-aware swizzle: dispatch is ~round-robin over 8 XCDs (lid%8); give each
// XCD a contiguous 8-row y-band so its 4MB L2 keeps the A band (2MB) resident
// and each B panel (256KB) is reused 8x back-to-back -> fabric reads drop
// ~768MB -> ~80MB for the qkv GEMM.
// Output: Cf!=null -> fp32 (+bias); else bf16 (+= addend fp32 if !=null).
// If vt!=null: tiles with col>=2048 (v band) are stored TRANSPOSED into
// vt[((b<<10)|vchan)<<10 | n] instead of Cb (fuses the V^T transpose).
__global__ __launch_bounds__(256) void gemm_bf16_nt(const bf16* __restrict__ A,
                                                    const bf16* __restrict__ B,
                                                    bf16* __restrict__ Cb,
                                                    float* __restrict__ Cf,
                                                    const float* __restrict__ addend,
                                                    const float* __restrict__ bias,
                                                    bf16* __restrict__ vt,
                                                    int N) {
  __shared__ bf16 As[4][128][8];   // [kchunk][m][8]  8KB
  __shared__ bf16 Bs[4][128][8];   // 8KB
  int t = threadIdx.x, w = t >> 6, lane = t & 63;
  int q15 = lane & 15, quad = lane >> 4;
  // XCD swizzle (bijective remap of the block grid; gridDim.y % 8 == 0)
  int lid = blockIdx.x + gridDim.x * blockIdx.y;
  int band = gridDim.y >> 3;
  int xcd = lid & 7, tt = lid >> 3;
  int by = xcd * band + tt % band;
  int bx = tt / band;
  int m0 = by * 128, n0 = bx * 128;
  int wm = (w >> 1) * 64, wn = (w & 1) * 64;
  floatx4 acc[4][4];
#pragma unroll
  for (int i = 0; i < 4; ++i)
#pragma unroll
    for (int j = 0; j < 4; ++j) acc[i][j] = (floatx4){0.f, 0.f, 0.f, 0.f};

  const bf16* Ag = A + (size_t)(m0 + lane) * 1024 + w * 8;
  const bf16* Bg = B + (size_t)(n0 + lane) * 1024 + w * 8;

  for (int k0 = 0; k0 < 1024; k0 += 32) {
    __syncthreads();
    async_load16(Ag + k0,             &As[w][0][0]);
    async_load16(Ag + 64 * 1024 + k0, &As[w][64][0]);
    async_load16(Bg + k0,             &Bs[w][0][0]);
    async_load16(Bg + 64 * 1024 + k0, &Bs[w][64][0]);
    __syncthreads();
    bf16x8 af[4], bfr[4];
#pragma unroll
    for (int i = 0; i < 4; ++i) af[i]  = *(const bf16x8*)&As[quad][wm + i * 16 + q15][0];
#pragma unroll
    for (int j = 0; j < 4; ++j) bfr[j] = *(const bf16x8*)&Bs[quad][wn + j * 16 + q15][0];
#pragma unroll
    for (int i = 0; i < 4; ++i)
#pragma unroll
      for (int j = 0; j < 4; ++j) acc[i][j] = mfma16(af[i], bfr[j], acc[i][j]);
  }

  if (vt && (n0 + wn) >= 2048) {
    // v band: store transposed into Vt. acc[i][j][0..3] = 4 consecutive
    // x-rows (n dim) at fixed channel -> contiguous bf16x4 in Vt.
#pragma unroll
    for (int i = 0; i < 4; ++i) {
      int gm = m0 + wm + i * 16 + quad * 4;          // x row (4 consecutive)
      int b = gm >> 10, n = gm & 1023;
#pragma unroll
      for (int j = 0; j < 4; ++j) {
        int vchan = (n0 + wn - 2048) + j * 16 + q15; // h*64+d
        bf16x4 pk = {(__bf16)acc[i][j][0], (__bf16)acc[i][j][1],
                     (__bf16)acc[i][j][2], (__bf16)acc[i][j][3]};
        *(bf16x4*)&vt[((((size_t)b << 10) | vchan) << 10) | n] = pk;
      }
    }
    return;
  }

#pragma unroll
  for (int i = 0; i < 4; ++i)
#pragma unroll
    for (int r = 0; r < 4; ++r) {
      int gm = m0 + wm + i * 16 + quad * 4 + r;
      size_t rowo = (size_t)gm * N + n0 + wn;
#pragma unroll
      for (int j = 0; j < 4; ++j) {
        int col = j * 16 + q15;
        float v = acc[i][j][r];
        if (Cf) {
          Cf[rowo + col] = v + (bias ? bias[n0 + wn + col] : 0.f);
        } else {
          if (addend) v += addend[rowo + col];
          Cb[rowo + col] = (__bf16)v;
        }
      }
    }
}

// ---------------------------------------------------------------------------
// Flash attention, S^T formulation. Block = (b,h,128 q rows), 4 waves, each
// wave owns 32 q columns of S^T. kv-tiles of 64 keys.
// XCD swizzle: all 8 q-tiles of a (b,h) land on one XCD (bh = xcd mod 8) so
// the K/V panels (256KB) are fetched once per XCD instead of 8x.
__global__ __launch_bounds__(256) void attn_mfma(const bf16* __restrict__ qkvb,
                                                 const bf16* __restrict__ Vt,
                                                 bf16* __restrict__ attn_out) {
  __shared__ __align__(16) char smem[49152];
  bf16 (*Qs)[128][8] = (bf16(*)[128][8])smem;            // 16KB [dchunk][q][8]
  bf16 (*Ks)[64][8]  = (bf16(*)[64][8])(smem + 16384);   // 8KB  [dchunk][key][8]
  bf16 (*Vs)[64][8]  = (bf16(*)[64][8])(smem + 24576);   // 8KB  [keychunk][d][8]
  bf16* PsB = (bf16*)(smem + 32768);                     // 16KB [w][nt][kc][q16][8]

  int t = threadIdx.x, w = t >> 6, lane = t & 63;
  int q15 = lane & 15, quad = lane >> 4;
  // swizzle: lid in [0,1024): xcd=lid&7, r=lid>>3; q-tile=r&7, bh=xcd+8*(r>>3)
  int lid = blockIdx.x + (blockIdx.y << 3);
  int xcd = lid & 7, rr = lid >> 3;
  int q0 = (rr & 7) * 128;
  int bh = xcd + ((rr >> 3) << 3);
  int b = bh >> 4, h = bh & 15;
  const float scale = 0.125f;

  const bf16* Qg = qkvb + (size_t)(b * 1024 + q0) * 3072 + h * 64;
  const bf16* Kg = qkvb + (size_t)(b * 1024) * 3072 + 1024 + h * 64;
  const bf16* Vg = Vt + (size_t)(bh * 64) * 1024;

#pragma unroll
  for (int cc = 0; cc < 2; ++cc) {
    int kc = w * 2 + cc;
    async_load16(Qg + (size_t)lane * 3072 + kc * 8,        &Qs[kc][0][0]);
    async_load16(Qg + (size_t)(64 + lane) * 3072 + kc * 8, &Qs[kc][64][0]);
  }

  floatx4 oacc[4][2];
  float m_i[2], l_i[2];
#pragma unroll
  for (int nt = 0; nt < 2; ++nt) {
    m_i[nt] = -INFINITY; l_i[nt] = 0.f;
#pragma unroll
    for (int mt = 0; mt < 4; ++mt) oacc[mt][nt] = (floatx4){0.f, 0.f, 0.f, 0.f};
  }

  for (int kt = 0; kt < 16; ++kt) {
    int kv0 = kt * 64;
    __syncthreads();
    const bf16* Kg2 = Kg + (size_t)(kv0 + lane) * 3072;
    const bf16* Vg2 = Vg + (size_t)lane * 1024 + kv0;
    async_load16(Kg2 + (w * 2) * 8,     &Ks[w * 2][0][0]);
    async_load16(Kg2 + (w * 2 + 1) * 8, &Ks[w * 2 + 1][0][0]);
    async_load16(Vg2 + (w * 2) * 8,     &Vs[w * 2][0][0]);
    async_load16(Vg2 + (w * 2 + 1) * 8, &Vs[w * 2 + 1][0][0]);
    __syncthreads();

    floatx4 sacc[4][2];
#pragma unroll
    for (int mt = 0; mt < 4; ++mt)
#pragma unroll
      for (int nt = 0; nt < 2; ++nt) sacc[mt][nt] = (floatx4){0.f, 0.f, 0.f, 0.f};
#pragma unroll
    for (int ks = 0; ks < 2; ++ks) {
      bf16x8 kf[4], qf[2];
#pragma unroll
      for (int mt = 0; mt < 4; ++mt)
        kf[mt] = *(const bf16x8*)&Ks[ks * 4 + quad][mt * 16 + q15][0];
#pragma unroll
      for (int nt = 0; nt < 2; ++nt)
        qf[nt] = *(const bf16x8*)&Qs[ks * 4 + quad][w * 32 + nt * 16 + q15][0];
#pragma unroll
      for (int mt = 0; mt < 4; ++mt)
#pragma unroll
        for (int nt = 0; nt < 2; ++nt) sacc[mt][nt] = mfma16(kf[mt], qf[nt], sacc[mt][nt]);
    }

#pragma unroll
    for (int nt = 0; nt < 2; ++nt) {
      float mx = -INFINITY;
#pragma unroll
      for (int mt = 0; mt < 4; ++mt)
#pragma unroll
        for (int r = 0; r < 4; ++r) mx = fmaxf(mx, sacc[mt][nt][r]);
      mx = fmaxf(mx, __shfl_xor(mx, 16));
      mx = fmaxf(mx, __shfl_xor(mx, 32));
      float mnew = fmaxf(m_i[nt], mx * scale);
      float alpha = __expf(m_i[nt] - mnew);
      float rsum = 0.f;
#pragma unroll
      for (int mt = 0; mt < 4; ++mt)
#pragma unroll
        for (int r = 0; r < 4; ++r) {
          float p = __expf(sacc[mt][nt][r] * scale - mnew);
          sacc[mt][nt][r] = p;
          rsum += p;
        }
      rsum += __shfl_xor(rsum, 16);
      rsum += __shfl_xor(rsum, 32);
      l_i[nt] = l_i[nt] * alpha + rsum;
      m_i[nt] = mnew;
#pragma unroll
      for (int mt = 0; mt < 4; ++mt)
#pragma unroll
        for (int r = 0; r < 4; ++r) oacc[mt][nt][r] *= alpha;
    }

#pragma unroll
    for (int nt = 0; nt < 2; ++nt)
#pragma unroll
      for (int mt = 0; mt < 4; ++mt) {
        bf16x4 pk = {(__bf16)sacc[mt][nt][0], (__bf16)sacc[mt][nt][1],
                     (__bf16)sacc[mt][nt][2], (__bf16)sacc[mt][nt][3]};
        int kc = mt * 2 + (quad >> 1);
        *(bf16x4*)&PsB[(size_t)(w * 2 + nt) * 1024 + kc * 128 + q15 * 8 + (quad & 1) * 4] = pk;
      }

#pragma unroll
    for (int ks = 0; ks < 2; ++ks) {
      bf16x8 vf[4], pf[2];
#pragma unroll
      for (int mt = 0; mt < 4; ++mt)
        vf[mt] = *(const bf16x8*)&Vs[ks * 4 + quad][mt * 16 + q15][0];
#pragma unroll
      for (int nt = 0; nt < 2; ++nt)
        pf[nt] = *(const bf16x8*)&PsB[(size_t)(w * 2 + nt) * 1024 + (ks * 4 + quad) * 128 + q15 * 8];
#pragma unroll
      for (int mt = 0; mt < 4; ++mt)
#pragma unroll
        for (int nt = 0; nt < 2; ++nt) oacc[mt][nt] = mfma16(vf[mt], pf[nt], oacc[mt][nt]);
    }
  }

  __syncthreads();
  bf16* T = (bf16*)smem + w * 2304;   // [32 q][72]
#pragma unroll
  for (int nt = 0; nt < 2; ++nt) {
    float inv = 1.f / l_i[nt];
#pragma unroll
    for (int mt = 0; mt < 4; ++mt) {
      bf16x4 pk = {(__bf16)(oacc[mt][nt][0] * inv), (__bf16)(oacc[mt][nt][1] * inv),
                   (__bf16)(oacc[mt][nt][2] * inv), (__bf16)(oacc[mt][nt][3] * inv)};
      *(bf16x4*)&T[(nt * 16 + q15) * 72 + mt * 16 + quad * 4] = pk;
    }
  }
  int row = lane >> 1, ch = (lane & 1) * 32;
  const bf16* Tr = T + row * 72 + ch;
  bf16* outp = attn_out + (size_t)(b * 1024 + q0 + w * 32 + row) * 1024 + h * 64 + ch;
#pragma unroll
  for (int i = 0; i < 4; ++i) *(bf16x8*)&outp[i * 8] = *(const bf16x8*)&Tr[i * 8];
}

// ---------------------------------------------------------------------------
extern "C" void kernel_launch(void* const* d_in, const int* in_sizes, int n_in,
                              void* d_out, int out_size, void* d_ws, size_t ws_size,
                              hipStream_t stream) {
  (void)in_sizes; (void)n_in; (void)out_size; (void)ws_size;
  const float* x       = (const float*)d_in[0];   // 8x1024x1024
  const float* W_qkv   = (const float*)d_in[1];   // 3072x1024
  const float* W_proj  = (const float*)d_in[2];   // 1024x1024
  const float* b_proj  = (const float*)d_in[3];   // 1024
  const float* coef_k  = (const float*)d_in[4];   // 10x3000
  const float* coef_v  = (const float*)d_in[5];   // 10x3000
  const int*   indices = (const int*)d_in[6];     // 10x3000
  const int*   task    = (const int*)d_in[7];     // scalar

  // Workspace (104 MB peak). attn_out aliases the dead Bm/U/Ub region.
  char* w8 = (char*)d_ws;
  float* Bm     = (float*)(w8);                  // 4MB
  float* U      = (float*)(w8 + (4u  << 20));    // 8MB (k,v planes)
  bf16*  Ub     = (bf16*) (w8 + (12u << 20));    // 4MB [2048][1024]
  bf16*  Bmtb   = (bf16*) (w8 + (16u << 20));    // 2MB
  bf16*  Wcb    = (bf16*) (w8 + (18u << 20));    // 6MB [3072][1024]
  bf16*  xb     = (bf16*) (w8 + (24u << 20));    // 16MB
  bf16*  qkvb   = (bf16*) (w8 + (40u << 20));    // 48MB [8192][3072]
  bf16*  Vt     = (bf16*) (w8 + (88u << 20));    // 16MB [128][64][1024]
  bf16*  attnout= (bf16*) (w8);                  // 16MB alias (Bm/U/Ub dead)

  dct_kernel<<<4096, 256, 0, stream>>>(Bm, Bmtb);

  hipMemsetAsync(U, 0, (size_t)8 << 20, stream);
  scatter2<<<10 * NFRQ, 256, 0, stream>>>(coef_k, coef_v, indices, task, Bm, U);
  transpose_u<<<dim3(16, 32), 256, 0, stream>>>(U, Ub);

  conv_bf16<<<1024, 256, 0, stream>>>(W_qkv, Wcb, 262144);
  conv_bf16<<<8192, 256, 0, stream>>>(x, xb, 2097152);

  // k,v bands: Wcb[1024+m][n] = sum_c Ub[m][c]*Bmtb[n][c] + W_qkv[1024+m][n]
  gemm_bf16_nt<<<dim3(8, 16), 256, 0, stream>>>(Ub, Bmtb, Wcb + (1u << 20), nullptr,
                                                W_qkv + (1u << 20), nullptr, nullptr, 1024);

  // W_proj -> bf16 (into Bmtb slot, dead after lora GEMM)
  bf16* Wprojb = Bmtb;
  conv_bf16<<<1024, 256, 0, stream>>>(W_proj, Wprojb, 262144);

  // qkv = xb @ Wcb^T -> q,k bands bf16 into qkvb; v band transposed into Vt
  gemm_bf16_nt<<<dim3(24, 64), 256, 0, stream>>>(xb, Wcb, qkvb, nullptr,
                                                 nullptr, nullptr, Vt, 3072);

  // attention
  attn_mfma<<<dim3(8, 128), 256, 0, stream>>>(qkvb, Vt, attnout);

  // out = attn_out @ W_proj^T + b_proj  (fp32 out)
  gemm_bf16_nt<<<dim3(8, 64), 256, 0, stream>>>(attnout, Wprojb, nullptr, (float*)d_out,
                                                nullptr, b_proj, nullptr, 1024);
}

// Round 7
// 473.891 us; speedup vs baseline: 1.0656x; 1.0515x over previous
//
#include <hip/hip_runtime.h>
#include <math.h>

// B=8, N=1024, C=1024, H=16, hd=64, n_tasks=10, n_frq=3000
#define NFRQ 3000

typedef __bf16 bf16;
typedef __attribute__((ext_vector_type(8))) __bf16 bf16x8;
typedef __attribute__((ext_vector_type(4))) __bf16 bf16x4;
typedef __attribute__((ext_vector_type(4))) float floatx4;

__device__ __forceinline__ floatx4 mfma16(bf16x8 a, bf16x8 b, floatx4 c) {
  return __builtin_amdgcn_mfma_f32_16x16x32_bf16(a, b, c, 0, 0, 0);
}

// async global->LDS, 16B per lane, dest = base + lane*16
__device__ __forceinline__ void async_load16(const bf16* g, bf16* l) {
  __builtin_amdgcn_global_load_lds(
      (const __attribute__((address_space(1))) unsigned int*)g,
      (__attribute__((address_space(3))) unsigned int*)l, 16, 0, 0);
}

__device__ __forceinline__ float fexp2(float x) {
  return __builtin_amdgcn_exp2f(x);
}

// ---------------------------------------------------------------------------
// DCT-II orthonormal matrix, transposed, bf16: Bmtb[j][i] = Bm[i][j].
// Exact integer angle reduction: i*(2j+1) mod 4096.
__global__ __launch_bounds__(256) void dct_kernel(bf16* __restrict__ Bmtb) {
  int t = blockIdx.x * 256 + threadIdx.x;  // 0..1M-1
  int j = t >> 10, i = t & 1023;           // output [j][i] = Bm[i][j]
  const float cst = 0.04419417382415922f;  // sqrt(2)/32
  const float w = 1.5339807878856412e-3f;  // pi/2048
  int K = (i * (2 * j + 1)) & 4095;
  float v = (i == 0) ? 0.03125f : cst * __cosf((float)K * w);
  Bmtb[t] = (__bf16)v;
}

// ---------------------------------------------------------------------------
// Dense scatter: S[id] += coef (2 fp32 planes, k and v). One thread per nz.
__global__ __launch_bounds__(256) void scatter_s(const float* __restrict__ coef_k,
                                                 const float* __restrict__ coef_v,
                                                 const int* __restrict__ idx,
                                                 const int* __restrict__ task,
                                                 float* __restrict__ S) {
  int nz = blockIdx.x * 256 + threadIdx.x;
  if (nz >= 10 * NFRQ || nz >= (*task + 1) * NFRQ) return;
  int id = idx[nz];
  atomicAdd(S + id, coef_k[nz]);
  atomicAdd(S + (1u << 20) + id, coef_v[nz]);
}

// ---------------------------------------------------------------------------
// fp32 -> bf16 convert (optional scale), n4 = n/4 float4 chunks
__global__ __launch_bounds__(256) void conv_bf16(const float* __restrict__ s,
                                                 bf16* __restrict__ d, int n4,
                                                 float scale) {
  int i = blockIdx.x * 256 + threadIdx.x;
  if (i >= n4) return;
  float4 f = ((const float4*)s)[i];
  bf16x4 o = {(__bf16)(f.x * scale), (__bf16)(f.y * scale),
              (__bf16)(f.z * scale), (__bf16)(f.w * scale)};
  *(bf16x4*)&d[(size_t)i * 4] = o;
}

// ---------------------------------------------------------------------------
// MFMA NT GEMM: C[m][n] = sum_k A[m][k]*B[n][k], K=1024 fixed, ldc=N.
// 128x128 block tile, 4 waves each 64x64 (4x4 of 16x16x32), BK=32, 16KB LDS.
// XCD-aware swizzle (R6: FETCH -36%): contiguous y-band per XCD.
// Output: Cf!=null -> fp32 (+bias); else bf16 (+= addend fp32 if !=null).
// If vt!=null: tiles with col>=vt_col0 are stored TRANSPOSED into
// vt[((p<<10)|vchan)<<10 | m] where p=row>>10, m=row&1023, vchan=col-vt_col0.
//   - qkv:   vt_col0=2048 fuses the V^T transpose (p=batch, vchan=h*64+d)
//   - lora1: vt_col0=0 stores T = S@Bm transposed per plane
__global__ __launch_bounds__(256) void gemm_bf16_nt(const bf16* __restrict__ A,
                                                    const bf16* __restrict__ B,
                                                    bf16* __restrict__ Cb,
                                                    float* __restrict__ Cf,
                                                    const float* __restrict__ addend,
                                                    const float* __restrict__ bias,
                                                    bf16* __restrict__ vt,
                                                    int vt_col0,
                                                    int N) {
  __shared__ bf16 As[4][128][8];   // [kchunk][m][8]  8KB
  __shared__ bf16 Bs[4][128][8];   // 8KB
  int t = threadIdx.x, w = t >> 6, lane = t & 63;
  int q15 = lane & 15, quad = lane >> 4;
  // XCD swizzle (bijective remap of the block grid; gridDim.y % 8 == 0)
  int lid = blockIdx.x + gridDim.x * blockIdx.y;
  int band = gridDim.y >> 3;
  int xcd = lid & 7, tt = lid >> 3;
  int by = xcd * band + tt % band;
  int bx = tt / band;
  int m0 = by * 128, n0 = bx * 128;
  int wm = (w >> 1) * 64, wn = (w & 1) * 64;
  floatx4 acc[4][4];
#pragma unroll
  for (int i = 0; i < 4; ++i)
#pragma unroll
    for (int j = 0; j < 4; ++j) acc[i][j] = (floatx4){0.f, 0.f, 0.f, 0.f};

  const bf16* Ag = A + (size_t)(m0 + lane) * 1024 + w * 8;
  const bf16* Bg = B + (size_t)(n0 + lane) * 1024 + w * 8;

  for (int k0 = 0; k0 < 1024; k0 += 32) {
    __syncthreads();
    async_load16(Ag + k0,             &As[w][0][0]);
    async_load16(Ag + 64 * 1024 + k0, &As[w][64][0]);
    async_load16(Bg + k0,             &Bs[w][0][0]);
    async_load16(Bg + 64 * 1024 + k0, &Bs[w][64][0]);
    __syncthreads();
    bf16x8 af[4], bfr[4];
#pragma unroll
    for (int i = 0; i < 4; ++i) af[i]  = *(const bf16x8*)&As[quad][wm + i * 16 + q15][0];
#pragma unroll
    for (int j = 0; j < 4; ++j) bfr[j] = *(const bf16x8*)&Bs[quad][wn + j * 16 + q15][0];
#pragma unroll
    for (int i = 0; i < 4; ++i)
#pragma unroll
      for (int j = 0; j < 4; ++j) acc[i][j] = mfma16(af[i], bfr[j], acc[i][j]);
  }

  if (vt && (n0 + wn) >= vt_col0) {
    // transposed store: acc[i][j][0..3] = 4 consecutive rows at one col
    // -> contiguous bf16x4 along the transposed minor dim.
#pragma unroll
    for (int i = 0; i < 4; ++i) {
      int gm = m0 + wm + i * 16 + quad * 4;          // row (4 consecutive)
      int p = gm >> 10, mi = gm & 1023;
#pragma unroll
      for (int j = 0; j < 4; ++j) {
        int vchan = (n0 + wn - vt_col0) + j * 16 + q15;
        bf16x4 pk = {(__bf16)acc[i][j][0], (__bf16)acc[i][j][1],
                     (__bf16)acc[i][j][2], (__bf16)acc[i][j][3]};
        *(bf16x4*)&vt[((((size_t)p << 10) | vchan) << 10) | mi] = pk;
      }
    }
    return;
  }

#pragma unroll
  for (int i = 0; i < 4; ++i)
#pragma unroll
    for (int r = 0; r < 4; ++r) {
      int gm = m0 + wm + i * 16 + quad * 4 + r;
      size_t rowo = (size_t)gm * N + n0 + wn;
#pragma unroll
      for (int j = 0; j < 4; ++j) {
        int col = j * 16 + q15;
        float v = acc[i][j][r];
        if (Cf) {
          Cf[rowo + col] = v + (bias ? bias[n0 + wn + col] : 0.f);
        } else {
          if (addend) v += addend[rowo + col];
          Cb[rowo + col] = (__bf16)v;
        }
      }
    }
}

// ---------------------------------------------------------------------------
// Flash attention, S^T formulation. Block = (b,h,128 q rows), 4 waves, each
// wave owns 32 q columns of S^T. kv-tiles of 64 keys.
// Q is PRE-SCALED by 0.125*log2(e) (folded into Wcb q band), so softmax is
// pure max + exp2 (v_exp_f32 is natively 2^x) -- no per-element multiplies.
// XCD swizzle: all 8 q-tiles of a (b,h) land on one XCD.
__global__ __launch_bounds__(256) void attn_mfma(const bf16* __restrict__ qkvb,
                                                 const bf16* __restrict__ Vt,
                                                 bf16* __restrict__ attn_out) {
  __shared__ __align__(16) char smem[49152];
  bf16 (*Qs)[128][8] = (bf16(*)[128][8])smem;            // 16KB [dchunk][q][8]
  bf16 (*Ks)[64][8]  = (bf16(*)[64][8])(smem + 16384);   // 8KB  [dchunk][key][8]
  bf16 (*Vs)[64][8]  = (bf16(*)[64][8])(smem + 24576);   // 8KB  [keychunk][d][8]
  bf16* PsB = (bf16*)(smem + 32768);                     // 16KB [w][nt][kc][q16][8]

  int t = threadIdx.x, w = t >> 6, lane = t & 63;
  int q15 = lane & 15, quad = lane >> 4;
  // swizzle: lid in [0,1024): xcd=lid&7, r=lid>>3; q-tile=r&7, bh=xcd+8*(r>>3)
  int lid = blockIdx.x + (blockIdx.y << 3);
  int xcd = lid & 7, rr = lid >> 3;
  int q0 = (rr & 7) * 128;
  int bh = xcd + ((rr >> 3) << 3);
  int b = bh >> 4, h = bh & 15;

  const bf16* Qg = qkvb + (size_t)(b * 1024 + q0) * 3072 + h * 64;
  const bf16* Kg = qkvb + (size_t)(b * 1024) * 3072 + 1024 + h * 64;
  const bf16* Vg = Vt + (size_t)(bh * 64) * 1024;

#pragma unroll
  for (int cc = 0; cc < 2; ++cc) {
    int kc = w * 2 + cc;
    async_load16(Qg + (size_t)lane * 3072 + kc * 8,        &Qs[kc][0][0]);
    async_load16(Qg + (size_t)(64 + lane) * 3072 + kc * 8, &Qs[kc][64][0]);
  }

  floatx4 oacc[4][2];
  float m_i[2], l_i[2];
#pragma unroll
  for (int nt = 0; nt < 2; ++nt) {
    m_i[nt] = -INFINITY; l_i[nt] = 0.f;
#pragma unroll
    for (int mt = 0; mt < 4; ++mt) oacc[mt][nt] = (floatx4){0.f, 0.f, 0.f, 0.f};
  }

  for (int kt = 0; kt < 16; ++kt) {
    int kv0 = kt * 64;
    __syncthreads();
    const bf16* Kg2 = Kg + (size_t)(kv0 + lane) * 3072;
    const bf16* Vg2 = Vg + (size_t)lane * 1024 + kv0;
    async_load16(Kg2 + (w * 2) * 8,     &Ks[w * 2][0][0]);
    async_load16(Kg2 + (w * 2 + 1) * 8, &Ks[w * 2 + 1][0][0]);
    async_load16(Vg2 + (w * 2) * 8,     &Vs[w * 2][0][0]);
    async_load16(Vg2 + (w * 2 + 1) * 8, &Vs[w * 2 + 1][0][0]);
    __syncthreads();

    floatx4 sacc[4][2];
#pragma unroll
    for (int mt = 0; mt < 4; ++mt)
#pragma unroll
      for (int nt = 0; nt < 2; ++nt) sacc[mt][nt] = (floatx4){0.f, 0.f, 0.f, 0.f};
#pragma unroll
    for (int ks = 0; ks < 2; ++ks) {
      bf16x8 kf[4], qf[2];
#pragma unroll
      for (int mt = 0; mt < 4; ++mt)
        kf[mt] = *(const bf16x8*)&Ks[ks * 4 + quad][mt * 16 + q15][0];
#pragma unroll
      for (int nt = 0; nt < 2; ++nt)
        qf[nt] = *(const bf16x8*)&Qs[ks * 4 + quad][w * 32 + nt * 16 + q15][0];
#pragma unroll
      for (int mt = 0; mt < 4; ++mt)
#pragma unroll
        for (int nt = 0; nt < 2; ++nt) sacc[mt][nt] = mfma16(kf[mt], qf[nt], sacc[mt][nt]);
    }

    // online softmax in log2 domain (logits pre-scaled by 0.125*log2e)
#pragma unroll
    for (int nt = 0; nt < 2; ++nt) {
      float mx = -INFINITY;
#pragma unroll
      for (int mt = 0; mt < 4; ++mt)
#pragma unroll
        for (int r = 0; r < 4; ++r) mx = fmaxf(mx, sacc[mt][nt][r]);
      mx = fmaxf(mx, __shfl_xor(mx, 16));
      mx = fmaxf(mx, __shfl_xor(mx, 32));
      float mnew = fmaxf(m_i[nt], mx);
      float alpha = fexp2(m_i[nt] - mnew);
      float rsum = 0.f;
#pragma unroll
      for (int mt = 0; mt < 4; ++mt)
#pragma unroll
        for (int r = 0; r < 4; ++r) {
          float p = fexp2(sacc[mt][nt][r] - mnew);
          sacc[mt][nt][r] = p;
          rsum += p;
        }
      rsum += __shfl_xor(rsum, 16);
      rsum += __shfl_xor(rsum, 32);
      l_i[nt] = l_i[nt] * alpha + rsum;
      m_i[nt] = mnew;
#pragma unroll
      for (int mt = 0; mt < 4; ++mt)
#pragma unroll
        for (int r = 0; r < 4; ++r) oacc[mt][nt][r] *= alpha;
    }

#pragma unroll
    for (int nt = 0; nt < 2; ++nt)
#pragma unroll
      for (int mt = 0; mt < 4; ++mt) {
        bf16x4 pk = {(__bf16)sacc[mt][nt][0], (__bf16)sacc[mt][nt][1],
                     (__bf16)sacc[mt][nt][2], (__bf16)sacc[mt][nt][3]};
        int kc = mt * 2 + (quad >> 1);
        *(bf16x4*)&PsB[(size_t)(w * 2 + nt) * 1024 + kc * 128 + q15 * 8 + (quad & 1) * 4] = pk;
      }

#pragma unroll
    for (int ks = 0; ks < 2; ++ks) {
      bf16x8 vf[4], pf[2];
#pragma unroll
      for (int mt = 0; mt < 4; ++mt)
        vf[mt] = *(const bf16x8*)&Vs[ks * 4 + quad][mt * 16 + q15][0];
#pragma unroll
      for (int nt = 0; nt < 2; ++nt)
        pf[nt] = *(const bf16x8*)&PsB[(size_t)(w * 2 + nt) * 1024 + (ks * 4 + quad) * 128 + q15 * 8];
#pragma unroll
      for (int mt = 0; mt < 4; ++mt)
#pragma unroll
        for (int nt = 0; nt < 2; ++nt) oacc[mt][nt] = mfma16(vf[mt], pf[nt], oacc[mt][nt]);
    }
  }

  __syncthreads();
  bf16* T = (bf16*)smem + w * 2304;   // [32 q][72]
#pragma unroll
  for (int nt = 0; nt < 2; ++nt) {
    float inv = 1.f / l_i[nt];
#pragma unroll
    for (int mt = 0; mt < 4; ++mt) {
      bf16x4 pk = {(__bf16)(oacc[mt][nt][0] * inv), (__bf16)(oacc[mt][nt][1] * inv),
                   (__bf16)(oacc[mt][nt][2] * inv), (__bf16)(oacc[mt][nt][3] * inv)};
      *(bf16x4*)&T[(nt * 16 + q15) * 72 + mt * 16 + quad * 4] = pk;
    }
  }
  int row = lane >> 1, ch = (lane & 1) * 32;
  const bf16* Tr = T + row * 72 + ch;
  bf16* outp = attn_out + (size_t)(b * 1024 + q0 + w * 32 + row) * 1024 + h * 64 + ch;
#pragma unroll
  for (int i = 0; i < 4; ++i) *(bf16x8*)&outp[i * 8] = *(const bf16x8*)&Tr[i * 8];
}

// ---------------------------------------------------------------------------
extern "C" void kernel_launch(void* const* d_in, const int* in_sizes, int n_in,
                              void* d_out, int out_size, void* d_ws, size_t ws_size,
                              hipStream_t stream) {
  (void)in_sizes; (void)n_in; (void)out_size; (void)ws_size;
  const float* x       = (const float*)d_in[0];   // 8x1024x1024
  const float* W_qkv   = (const float*)d_in[1];   // 3072x1024
  const float* W_proj  = (const float*)d_in[2];   // 1024x1024
  const float* b_proj  = (const float*)d_in[3];   // 1024
  const float* coef_k  = (const float*)d_in[4];   // 10x3000
  const float* coef_v  = (const float*)d_in[5];   // 10x3000
  const int*   indices = (const int*)d_in[6];     // 10x3000
  const int*   task    = (const int*)d_in[7];     // scalar

  // Workspace (104 MB peak). attn_out aliases the dead S/S2b/Tt region.
  char* w8 = (char*)d_ws;
  float* Sf     = (float*)(w8);                  // 8MB  (2 fp32 planes, transient)
  bf16*  S2b    = (bf16*) (w8 + (8u  << 20));    // 4MB  [2048][1024] (transient)
  bf16*  Tt     = (bf16*) (w8 + (12u << 20));    // 4MB  [2][1024][1024] (transient)
  bf16*  Bmtb   = (bf16*) (w8 + (16u << 20));    // 2MB  (later reused for W_proj bf16)
  bf16*  Wcb    = (bf16*) (w8 + (18u << 20));    // 6MB  [3072][1024]
  bf16*  xb     = (bf16*) (w8 + (24u << 20));    // 16MB
  bf16*  qkvb   = (bf16*) (w8 + (40u << 20));    // 48MB [8192][3072]
  bf16*  Vt     = (bf16*) (w8 + (88u << 20));    // 16MB [128][64][1024]
  bf16*  attnout= (bf16*) (w8);                  // 16MB alias (Sf/S2b/Tt dead)

  const float QSCALE = 0.18033688011112042f;  // 0.125 * log2(e)

  dct_kernel<<<4096, 256, 0, stream>>>(Bmtb);

  // Dense S scatter (fp32), then convert to bf16 stacked planes
  hipMemsetAsync(Sf, 0, (size_t)8 << 20, stream);
  scatter_s<<<118, 256, 0, stream>>>(coef_k, coef_v, indices, task, Sf);
  conv_bf16<<<2048, 256, 0, stream>>>(Sf, S2b, 524288, 1.0f);

  // Wcb q band = W_qkv q band * QSCALE (scale folded into logits)
  conv_bf16<<<1024, 256, 0, stream>>>(W_qkv, Wcb, 262144, QSCALE);
  conv_bf16<<<8192, 256, 0, stream>>>(x, xb, 2097152, 1.0f);

  // LoRA: T = S @ Bm (stored transposed per plane), W_band = Bm^T @ T + W_qkv
  gemm_bf16_nt<<<dim3(8, 16), 256, 0, stream>>>(S2b, Bmtb, nullptr, nullptr,
                                                nullptr, nullptr, Tt, 0, 1024);
  gemm_bf16_nt<<<dim3(8, 8), 256, 0, stream>>>(Bmtb, Tt, Wcb + (1u << 20), nullptr,
                                               W_qkv + (1u << 20), nullptr, nullptr,
                                               1 << 30, 1024);
  gemm_bf16_nt<<<dim3(8, 8), 256, 0, stream>>>(Bmtb, Tt + (1u << 20), Wcb + (2u << 20),
                                               nullptr, W_qkv + (2u << 20), nullptr,
                                               nullptr, 1 << 30, 1024);

  // W_proj -> bf16 (into Bmtb slot, dead after the lora GEMMs)
  bf16* Wprojb = Bmtb;
  conv_bf16<<<1024, 256, 0, stream>>>(W_proj, Wprojb, 262144, 1.0f);

  // qkv = xb @ Wcb^T -> q,k bands bf16 into qkvb; v band transposed into Vt
  gemm_bf16_nt<<<dim3(24, 64), 256, 0, stream>>>(xb, Wcb, qkvb, nullptr,
                                                 nullptr, nullptr, Vt, 2048, 3072);

  // attention
  attn_mfma<<<dim3(8, 128), 256, 0, stream>>>(qkvb, Vt, attnout);

  // out = attn_out @ W_proj^T + b_proj  (fp32 out)
  gemm_bf16_nt<<<dim3(8, 64), 256, 0, stream>>>(attnout, Wprojb, nullptr, (float*)d_out,
                                                nullptr, b_proj, nullptr, 1 << 30, 1024);
}

// Round 8
// 467.617 us; speedup vs baseline: 1.0799x; 1.0134x over previous
//
#include <hip/hip_runtime.h>
#include <math.h>

// B=8, N=1024, C=1024, H=16, hd=64, n_tasks=10, n_frq=3000
#define NFRQ 3000

typedef __bf16 bf16;
typedef __attribute__((ext_vector_type(8))) __bf16 bf16x8;
typedef __attribute__((ext_vector_type(4))) __bf16 bf16x4;
typedef __attribute__((ext_vector_type(4))) float floatx4;

__device__ __forceinline__ floatx4 mfma16(bf16x8 a, bf16x8 b, floatx4 c) {
  return __builtin_amdgcn_mfma_f32_16x16x32_bf16(a, b, c, 0, 0, 0);
}

// async global->LDS, 16B per lane, dest = base + lane*16
__device__ __forceinline__ void async_load16(const bf16* g, bf16* l) {
  __builtin_amdgcn_global_load_lds(
      (const __attribute__((address_space(1))) unsigned int*)g,
      (__attribute__((address_space(3))) unsigned int*)l, 16, 0, 0);
}

__device__ __forceinline__ float fexp2(float x) {
  return __builtin_amdgcn_exp2f(x);
}

// ---------------------------------------------------------------------------
// DCT-II orthonormal matrix, transposed, bf16: Bmtb[j][i] = Bm[i][j].
// Exact integer angle reduction: i*(2j+1) mod 4096.
__global__ __launch_bounds__(256) void dct_kernel(bf16* __restrict__ Bmtb) {
  int t = blockIdx.x * 256 + threadIdx.x;  // 0..1M-1
  int j = t >> 10, i = t & 1023;           // output [j][i] = Bm[i][j]
  const float cst = 0.04419417382415922f;  // sqrt(2)/32
  const float w = 1.5339807878856412e-3f;  // pi/2048
  int K = (i * (2 * j + 1)) & 4095;
  float v = (i == 0) ? 0.03125f : cst * __cosf((float)K * w);
  Bmtb[t] = (__bf16)v;
}

// ---------------------------------------------------------------------------
// Dense scatter: S[id] += coef (2 fp32 planes, k and v). One thread per nz.
__global__ __launch_bounds__(256) void scatter_s(const float* __restrict__ coef_k,
                                                 const float* __restrict__ coef_v,
                                                 const int* __restrict__ idx,
                                                 const int* __restrict__ task,
                                                 float* __restrict__ S) {
  int nz = blockIdx.x * 256 + threadIdx.x;
  if (nz >= 10 * NFRQ || nz >= (*task + 1) * NFRQ) return;
  int id = idx[nz];
  atomicAdd(S + id, coef_k[nz]);
  atomicAdd(S + (1u << 20) + id, coef_v[nz]);
}

// ---------------------------------------------------------------------------
// fp32 -> bf16 convert (optional scale), n4 = n/4 float4 chunks
__global__ __launch_bounds__(256) void conv_bf16(const float* __restrict__ s,
                                                 bf16* __restrict__ d, int n4,
                                                 float scale) {
  int i = blockIdx.x * 256 + threadIdx.x;
  if (i >= n4) return;
  float4 f = ((const float4*)s)[i];
  bf16x4 o = {(__bf16)(f.x * scale), (__bf16)(f.y * scale),
              (__bf16)(f.z * scale), (__bf16)(f.w * scale)};
  *(bf16x4*)&d[(size_t)i * 4] = o;
}

// ---------------------------------------------------------------------------
// MFMA NT GEMM: C[m][n] = sum_k A[m][k]*B[n][k], K=1024 fixed, ldc=N.
// 128x128 block tile, 4 waves each 64x64 (4x4 of 16x16x32), BK=32.
// LDS DOUBLE-BUFFER with cross-barrier prefetch: ONE barrier per K-step;
// loads for step it+1 are issued AFTER the barrier of step it, so their
// latency is covered by compute(it) instead of being drained immediately
// (the R7 structure exposed full L2 latency every step -> MfmaUtil 17%).
// XCD-aware swizzle (R6: FETCH -36%): contiguous y-band per XCD.
// Output: Cf!=null -> fp32 (+bias); else bf16 (+= addend fp32 if !=null).
// If vt!=null: tiles with col>=vt_col0 are stored TRANSPOSED into
// vt[((p<<10)|vchan)<<10 | m] (p=row>>10, m=row&1023, vchan=col-vt_col0).
__global__ __launch_bounds__(256) void gemm_bf16_nt(const bf16* __restrict__ A,
                                                    const bf16* __restrict__ B,
                                                    bf16* __restrict__ Cb,
                                                    float* __restrict__ Cf,
                                                    const float* __restrict__ addend,
                                                    const float* __restrict__ bias,
                                                    bf16* __restrict__ vt,
                                                    int vt_col0,
                                                    int N) {
  __shared__ bf16 As[2][4][128][8];   // 16KB (двойной буфер)
  __shared__ bf16 Bs[2][4][128][8];   // 16KB
  int t = threadIdx.x, w = t >> 6, lane = t & 63;
  int q15 = lane & 15, quad = lane >> 4;
  // XCD swizzle (bijective remap of the block grid; gridDim.y % 8 == 0)
  int lid = blockIdx.x + gridDim.x * blockIdx.y;
  int band = gridDim.y >> 3;
  int xcd = lid & 7, tt = lid >> 3;
  int by = xcd * band + tt % band;
  int bx = tt / band;
  int m0 = by * 128, n0 = bx * 128;
  int wm = (w >> 1) * 64, wn = (w & 1) * 64;
  floatx4 acc[4][4];
#pragma unroll
  for (int i = 0; i < 4; ++i)
#pragma unroll
    for (int j = 0; j < 4; ++j) acc[i][j] = (floatx4){0.f, 0.f, 0.f, 0.f};

  const bf16* Ag = A + (size_t)(m0 + lane) * 1024 + w * 8;
  const bf16* Bg = B + (size_t)(n0 + lane) * 1024 + w * 8;

  // prologue: stage K-step 0 into buffer 0
  async_load16(Ag,             &As[0][w][0][0]);
  async_load16(Ag + 64 * 1024, &As[0][w][64][0]);
  async_load16(Bg,             &Bs[0][w][0][0]);
  async_load16(Bg + 64 * 1024, &Bs[0][w][64][0]);

  for (int it = 0; it < 32; ++it) {
    int cur = it & 1;
    __syncthreads();   // drains loads(it) (issued one full compute phase ago)
    if (it + 1 < 32) {
      int k0 = (it + 1) * 32;
      async_load16(Ag + k0,             &As[cur ^ 1][w][0][0]);
      async_load16(Ag + 64 * 1024 + k0, &As[cur ^ 1][w][64][0]);
      async_load16(Bg + k0,             &Bs[cur ^ 1][w][0][0]);
      async_load16(Bg + 64 * 1024 + k0, &Bs[cur ^ 1][w][64][0]);
    }
    bf16x8 af[4], bfr[4];
#pragma unroll
    for (int i = 0; i < 4; ++i)
      af[i] = *(const bf16x8*)&As[cur][quad][wm + i * 16 + q15][0];
#pragma unroll
    for (int j = 0; j < 4; ++j)
      bfr[j] = *(const bf16x8*)&Bs[cur][quad][wn + j * 16 + q15][0];
#pragma unroll
    for (int i = 0; i < 4; ++i)
#pragma unroll
      for (int j = 0; j < 4; ++j) acc[i][j] = mfma16(af[i], bfr[j], acc[i][j]);
  }

  if (vt && (n0 + wn) >= vt_col0) {
    // transposed store: acc[i][j][0..3] = 4 consecutive rows at one col
#pragma unroll
    for (int i = 0; i < 4; ++i) {
      int gm = m0 + wm + i * 16 + quad * 4;          // row (4 consecutive)
      int p = gm >> 10, mi = gm & 1023;
#pragma unroll
      for (int j = 0; j < 4; ++j) {
        int vchan = (n0 + wn - vt_col0) + j * 16 + q15;
        bf16x4 pk = {(__bf16)acc[i][j][0], (__bf16)acc[i][j][1],
                     (__bf16)acc[i][j][2], (__bf16)acc[i][j][3]};
        *(bf16x4*)&vt[((((size_t)p << 10) | vchan) << 10) | mi] = pk;
      }
    }
    return;
  }

#pragma unroll
  for (int i = 0; i < 4; ++i)
#pragma unroll
    for (int r = 0; r < 4; ++r) {
      int gm = m0 + wm + i * 16 + quad * 4 + r;
      size_t rowo = (size_t)gm * N + n0 + wn;
#pragma unroll
      for (int j = 0; j < 4; ++j) {
        int col = j * 16 + q15;
        float v = acc[i][j][r];
        if (Cf) {
          Cf[rowo + col] = v + (bias ? bias[n0 + wn + col] : 0.f);
        } else {
          if (addend) v += addend[rowo + col];
          Cb[rowo + col] = (__bf16)v;
        }
      }
    }
}

// ---------------------------------------------------------------------------
// Flash attention, S^T formulation. Block = (b,h,128 q rows), 4 waves, each
// wave owns 32 q columns of S^T. kv-tiles of 64 keys.
// NO online softmax: logits (pre-scaled by 0.125*log2e via the Wcb q band)
// have |s| < ~15, so p = exp2(s) cannot overflow fp32 (needs s>120) and the
// max-shift cancels in p/l exactly. Removes all max/rescale VALU work.
// XCD swizzle: all 8 q-tiles of a (b,h) land on one XCD.
__global__ __launch_bounds__(256) void attn_mfma(const bf16* __restrict__ qkvb,
                                                 const bf16* __restrict__ Vt,
                                                 bf16* __restrict__ attn_out) {
  __shared__ __align__(16) char smem[49152];
  bf16 (*Qs)[128][8] = (bf16(*)[128][8])smem;            // 16KB [dchunk][q][8]
  bf16 (*Ks)[64][8]  = (bf16(*)[64][8])(smem + 16384);   // 8KB  [dchunk][key][8]
  bf16 (*Vs)[64][8]  = (bf16(*)[64][8])(smem + 24576);   // 8KB  [keychunk][d][8]
  bf16* PsB = (bf16*)(smem + 32768);                     // 16KB [w][nt][kc][q16][8]

  int t = threadIdx.x, w = t >> 6, lane = t & 63;
  int q15 = lane & 15, quad = lane >> 4;
  // swizzle: lid in [0,1024): xcd=lid&7, r=lid>>3; q-tile=r&7, bh=xcd+8*(r>>3)
  int lid = blockIdx.x + (blockIdx.y << 3);
  int xcd = lid & 7, rr = lid >> 3;
  int q0 = (rr & 7) * 128;
  int bh = xcd + ((rr >> 3) << 3);
  int b = bh >> 4, h = bh & 15;

  const bf16* Qg = qkvb + (size_t)(b * 1024 + q0) * 3072 + h * 64;
  const bf16* Kg = qkvb + (size_t)(b * 1024) * 3072 + 1024 + h * 64;
  const bf16* Vg = Vt + (size_t)(bh * 64) * 1024;

#pragma unroll
  for (int cc = 0; cc < 2; ++cc) {
    int kc = w * 2 + cc;
    async_load16(Qg + (size_t)lane * 3072 + kc * 8,        &Qs[kc][0][0]);
    async_load16(Qg + (size_t)(64 + lane) * 3072 + kc * 8, &Qs[kc][64][0]);
  }

  floatx4 oacc[4][2];
  float l_i[2] = {0.f, 0.f};
#pragma unroll
  for (int nt = 0; nt < 2; ++nt)
#pragma unroll
    for (int mt = 0; mt < 4; ++mt) oacc[mt][nt] = (floatx4){0.f, 0.f, 0.f, 0.f};

  for (int kt = 0; kt < 16; ++kt) {
    int kv0 = kt * 64;
    __syncthreads();
    const bf16* Kg2 = Kg + (size_t)(kv0 + lane) * 3072;
    const bf16* Vg2 = Vg + (size_t)lane * 1024 + kv0;
    async_load16(Kg2 + (w * 2) * 8,     &Ks[w * 2][0][0]);
    async_load16(Kg2 + (w * 2 + 1) * 8, &Ks[w * 2 + 1][0][0]);
    async_load16(Vg2 + (w * 2) * 8,     &Vs[w * 2][0][0]);
    async_load16(Vg2 + (w * 2 + 1) * 8, &Vs[w * 2 + 1][0][0]);
    __syncthreads();

    floatx4 sacc[4][2];
#pragma unroll
    for (int mt = 0; mt < 4; ++mt)
#pragma unroll
      for (int nt = 0; nt < 2; ++nt) sacc[mt][nt] = (floatx4){0.f, 0.f, 0.f, 0.f};
#pragma unroll
    for (int ks = 0; ks < 2; ++ks) {
      bf16x8 kf[4], qf[2];
#pragma unroll
      for (int mt = 0; mt < 4; ++mt)
        kf[mt] = *(const bf16x8*)&Ks[ks * 4 + quad][mt * 16 + q15][0];
#pragma unroll
      for (int nt = 0; nt < 2; ++nt)
        qf[nt] = *(const bf16x8*)&Qs[ks * 4 + quad][w * 32 + nt * 16 + q15][0];
#pragma unroll
      for (int mt = 0; mt < 4; ++mt)
#pragma unroll
        for (int nt = 0; nt < 2; ++nt) sacc[mt][nt] = mfma16(kf[mt], qf[nt], sacc[mt][nt]);
    }

    // softmax numerator: p = exp2(s), accumulate row sums (no max, no rescale)
#pragma unroll
    for (int nt = 0; nt < 2; ++nt) {
      float rsum = 0.f;
#pragma unroll
      for (int mt = 0; mt < 4; ++mt)
#pragma unroll
        for (int r = 0; r < 4; ++r) {
          float p = fexp2(sacc[mt][nt][r]);
          sacc[mt][nt][r] = p;
          rsum += p;
        }
      rsum += __shfl_xor(rsum, 16);
      rsum += __shfl_xor(rsum, 32);
      l_i[nt] += rsum;
    }

#pragma unroll
    for (int nt = 0; nt < 2; ++nt)
#pragma unroll
      for (int mt = 0; mt < 4; ++mt) {
        bf16x4 pk = {(__bf16)sacc[mt][nt][0], (__bf16)sacc[mt][nt][1],
                     (__bf16)sacc[mt][nt][2], (__bf16)sacc[mt][nt][3]};
        int kc = mt * 2 + (quad >> 1);
        *(bf16x4*)&PsB[(size_t)(w * 2 + nt) * 1024 + kc * 128 + q15 * 8 + (quad & 1) * 4] = pk;
      }

#pragma unroll
    for (int ks = 0; ks < 2; ++ks) {
      bf16x8 vf[4], pf[2];
#pragma unroll
      for (int mt = 0; mt < 4; ++mt)
        vf[mt] = *(const bf16x8*)&Vs[ks * 4 + quad][mt * 16 + q15][0];
#pragma unroll
      for (int nt = 0; nt < 2; ++nt)
        pf[nt] = *(const bf16x8*)&PsB[(size_t)(w * 2 + nt) * 1024 + (ks * 4 + quad) * 128 + q15 * 8];
#pragma unroll
      for (int mt = 0; mt < 4; ++mt)
#pragma unroll
        for (int nt = 0; nt < 2; ++nt) oacc[mt][nt] = mfma16(vf[mt], pf[nt], oacc[mt][nt]);
    }
  }

  __syncthreads();
  bf16* T = (bf16*)smem + w * 2304;   // [32 q][72]
#pragma unroll
  for (int nt = 0; nt < 2; ++nt) {
    float inv = 1.f / l_i[nt];
#pragma unroll
    for (int mt = 0; mt < 4; ++mt) {
      bf16x4 pk = {(__bf16)(oacc[mt][nt][0] * inv), (__bf16)(oacc[mt][nt][1] * inv),
                   (__bf16)(oacc[mt][nt][2] * inv), (__bf16)(oacc[mt][nt][3] * inv)};
      *(bf16x4*)&T[(nt * 16 + q15) * 72 + mt * 16 + quad * 4] = pk;
    }
  }
  int row = lane >> 1, ch = (lane & 1) * 32;
  const bf16* Tr = T + row * 72 + ch;
  bf16* outp = attn_out + (size_t)(b * 1024 + q0 + w * 32 + row) * 1024 + h * 64 + ch;
#pragma unroll
  for (int i = 0; i < 4; ++i) *(bf16x8*)&outp[i * 8] = *(const bf16x8*)&Tr[i * 8];
}

// ---------------------------------------------------------------------------
extern "C" void kernel_launch(void* const* d_in, const int* in_sizes, int n_in,
                              void* d_out, int out_size, void* d_ws, size_t ws_size,
                              hipStream_t stream) {
  (void)in_sizes; (void)n_in; (void)out_size; (void)ws_size;
  const float* x       = (const float*)d_in[0];   // 8x1024x1024
  const float* W_qkv   = (const float*)d_in[1];   // 3072x1024
  const float* W_proj  = (const float*)d_in[2];   // 1024x1024
  const float* b_proj  = (const float*)d_in[3];   // 1024
  const float* coef_k  = (const float*)d_in[4];   // 10x3000
  const float* coef_v  = (const float*)d_in[5];   // 10x3000
  const int*   indices = (const int*)d_in[6];     // 10x3000
  const int*   task    = (const int*)d_in[7];     // scalar

  // Workspace (104 MB peak). attn_out aliases the dead S/S2b/Tt region.
  char* w8 = (char*)d_ws;
  float* Sf     = (float*)(w8);                  // 8MB  (2 fp32 planes, transient)
  bf16*  S2b    = (bf16*) (w8 + (8u  << 20));    // 4MB  [2048][1024] (transient)
  bf16*  Tt     = (bf16*) (w8 + (12u << 20));    // 4MB  [2][1024][1024] (transient)
  bf16*  Bmtb   = (bf16*) (w8 + (16u << 20));    // 2MB  (later reused for W_proj bf16)
  bf16*  Wcb    = (bf16*) (w8 + (18u << 20));    // 6MB  [3072][1024]
  bf16*  xb     = (bf16*) (w8 + (24u << 20));    // 16MB
  bf16*  qkvb   = (bf16*) (w8 + (40u << 20));    // 48MB [8192][3072]
  bf16*  Vt     = (bf16*) (w8 + (88u << 20));    // 16MB [128][64][1024]
  bf16*  attnout= (bf16*) (w8);                  // 16MB alias (Sf/S2b/Tt dead)

  const float QSCALE = 0.18033688011112042f;  // 0.125 * log2(e)

  dct_kernel<<<4096, 256, 0, stream>>>(Bmtb);

  // Dense S scatter (fp32), then convert to bf16 stacked planes
  hipMemsetAsync(Sf, 0, (size_t)8 << 20, stream);
  scatter_s<<<118, 256, 0, stream>>>(coef_k, coef_v, indices, task, Sf);
  conv_bf16<<<2048, 256, 0, stream>>>(Sf, S2b, 524288, 1.0f);

  // Wcb q band = W_qkv q band * QSCALE (scale folded into logits)
  conv_bf16<<<1024, 256, 0, stream>>>(W_qkv, Wcb, 262144, QSCALE);
  conv_bf16<<<8192, 256, 0, stream>>>(x, xb, 2097152, 1.0f);

  // LoRA: T = S @ Bm (stored transposed per plane), W_band = Bm^T @ T + W_qkv
  gemm_bf16_nt<<<dim3(8, 16), 256, 0, stream>>>(S2b, Bmtb, nullptr, nullptr,
                                                nullptr, nullptr, Tt, 0, 1024);
  gemm_bf16_nt<<<dim3(8, 8), 256, 0, stream>>>(Bmtb, Tt, Wcb + (1u << 20), nullptr,
                                               W_qkv + (1u << 20), nullptr, nullptr,
                                               1 << 30, 1024);
  gemm_bf16_nt<<<dim3(8, 8), 256, 0, stream>>>(Bmtb, Tt + (1u << 20), Wcb + (2u << 20),
                                               nullptr, W_qkv + (2u << 20), nullptr,
                                               nullptr, 1 << 30, 1024);

  // W_proj -> bf16 (into Bmtb slot, dead after the lora GEMMs)
  bf16* Wprojb = Bmtb;
  conv_bf16<<<1024, 256, 0, stream>>>(W_proj, Wprojb, 262144, 1.0f);

  // qkv = xb @ Wcb^T -> q,k bands bf16 into qkvb; v band transposed into Vt
  gemm_bf16_nt<<<dim3(24, 64), 256, 0, stream>>>(xb, Wcb, qkvb, nullptr,
                                                 nullptr, nullptr, Vt, 2048, 3072);

  // attention
  attn_mfma<<<dim3(8, 128), 256, 0, stream>>>(qkvb, Vt, attnout);

  // out = attn_out @ W_proj^T + b_proj  (fp32 out)
  gemm_bf16_nt<<<dim3(8, 64), 256, 0, stream>>>(attnout, Wprojb, nullptr, (float*)d_out,
                                                nullptr, b_proj, nullptr, 1 << 30, 1024);
}

// Round 9
// 392.135 us; speedup vs baseline: 1.2877x; 1.1925x over previous
//
#include <hip/hip_runtime.h>
#include <math.h>

// B=8, N=1024, C=1024, H=16, hd=64, n_tasks=10, n_frq=3000
#define NFRQ 3000

typedef __bf16 bf16;
typedef __attribute__((ext_vector_type(8))) __bf16 bf16x8;
typedef __attribute__((ext_vector_type(4))) __bf16 bf16x4;
typedef __attribute__((ext_vector_type(4))) float floatx4;

__device__ __forceinline__ floatx4 mfma16(bf16x8 a, bf16x8 b, floatx4 c) {
  return __builtin_amdgcn_mfma_f32_16x16x32_bf16(a, b, c, 0, 0, 0);
}

// async global->LDS, 16B per lane, dest = base + lane*16
__device__ __forceinline__ void async_load16(const bf16* g, bf16* l) {
  __builtin_amdgcn_global_load_lds(
      (const __attribute__((address_space(1))) unsigned int*)g,
      (__attribute__((address_space(3))) unsigned int*)l, 16, 0, 0);
}

__device__ __forceinline__ float fexp2(float x) {
  return __builtin_amdgcn_exp2f(x);
}

// ---------------------------------------------------------------------------
// DCT-II orthonormal matrix, transposed, bf16: Bmtb[j][i] = Bm[i][j].
__global__ __launch_bounds__(256) void dct_kernel(bf16* __restrict__ Bmtb) {
  int t = blockIdx.x * 256 + threadIdx.x;  // 0..1M-1
  int j = t >> 10, i = t & 1023;           // output [j][i] = Bm[i][j]
  const float cst = 0.04419417382415922f;  // sqrt(2)/32
  const float w = 1.5339807878856412e-3f;  // pi/2048
  int K = (i * (2 * j + 1)) & 4095;
  float v = (i == 0) ? 0.03125f : cst * __cosf((float)K * w);
  Bmtb[t] = (__bf16)v;
}

// ---------------------------------------------------------------------------
// Dense scatter: S[id] += coef (2 fp32 planes, k and v). One thread per nz.
__global__ __launch_bounds__(256) void scatter_s(const float* __restrict__ coef_k,
                                                 const float* __restrict__ coef_v,
                                                 const int* __restrict__ idx,
                                                 const int* __restrict__ task,
                                                 float* __restrict__ S) {
  int nz = blockIdx.x * 256 + threadIdx.x;
  if (nz >= 10 * NFRQ || nz >= (*task + 1) * NFRQ) return;
  int id = idx[nz];
  atomicAdd(S + id, coef_k[nz]);
  atomicAdd(S + (1u << 20) + id, coef_v[nz]);
}

// ---------------------------------------------------------------------------
// fp32 -> bf16 convert (optional scale), n4 = n/4 float4 chunks
__global__ __launch_bounds__(256) void conv_bf16(const float* __restrict__ s,
                                                 bf16* __restrict__ d, int n4,
                                                 float scale) {
  int i = blockIdx.x * 256 + threadIdx.x;
  if (i >= n4) return;
  float4 f = ((const float4*)s)[i];
  bf16x4 o = {(__bf16)(f.x * scale), (__bf16)(f.y * scale),
              (__bf16)(f.z * scale), (__bf16)(f.w * scale)};
  *(bf16x4*)&d[(size_t)i * 4] = o;
}

// ---------------------------------------------------------------------------
// MFMA NT GEMM: C[m][n] = sum_k A[m][k]*B[n][k], K=1024 fixed, ldc=N.
// 128x128 block tile, 4 waves each 64x64 (4x4 of 16x16x32), BK=32,
// LDS double-buffer, cross-barrier prefetch, XCD-band swizzle (R6/R8).
// blockIdx.z: plane offset of 1M elements applied to B/Cb/addend (fuses the
// two LoRA band GEMMs into one launch).
// Output: Cf!=null -> fp32 (+bias); else bf16 (+= addend fp32 if !=null).
// If vt!=null: tiles with col>=vt_col0 stored TRANSPOSED into
// vt[((p<<10)|vchan)<<10 | m] (p=row>>10, m=row&1023, vchan=col-vt_col0).
__global__ __launch_bounds__(256) void gemm_bf16_nt(const bf16* __restrict__ A,
                                                    const bf16* __restrict__ B,
                                                    bf16* __restrict__ Cb,
                                                    float* __restrict__ Cf,
                                                    const float* __restrict__ addend,
                                                    const float* __restrict__ bias,
                                                    bf16* __restrict__ vt,
                                                    int vt_col0,
                                                    int N) {
  __shared__ bf16 As[2][4][128][8];   // 16KB (double buffer)
  __shared__ bf16 Bs[2][4][128][8];   // 16KB
  size_t zoff = (size_t)blockIdx.z << 20;
  B += zoff;
  if (Cb) Cb += zoff;
  if (addend) addend += zoff;
  int t = threadIdx.x, w = t >> 6, lane = t & 63;
  int q15 = lane & 15, quad = lane >> 4;
  // XCD swizzle (bijective remap of the block grid; gridDim.y % 8 == 0)
  int lid = blockIdx.x + gridDim.x * blockIdx.y;
  int band = gridDim.y >> 3;
  int xcd = lid & 7, tt = lid >> 3;
  int by = xcd * band + tt % band;
  int bx = tt / band;
  int m0 = by * 128, n0 = bx * 128;
  int wm = (w >> 1) * 64, wn = (w & 1) * 64;
  floatx4 acc[4][4];
#pragma unroll
  for (int i = 0; i < 4; ++i)
#pragma unroll
    for (int j = 0; j < 4; ++j) acc[i][j] = (floatx4){0.f, 0.f, 0.f, 0.f};

  const bf16* Ag = A + (size_t)(m0 + lane) * 1024 + w * 8;
  const bf16* Bg = B + (size_t)(n0 + lane) * 1024 + w * 8;

  // prologue: stage K-step 0 into buffer 0
  async_load16(Ag,             &As[0][w][0][0]);
  async_load16(Ag + 64 * 1024, &As[0][w][64][0]);
  async_load16(Bg,             &Bs[0][w][0][0]);
  async_load16(Bg + 64 * 1024, &Bs[0][w][64][0]);

  for (int it = 0; it < 32; ++it) {
    int cur = it & 1;
    __syncthreads();   // drains loads(it) (issued one full compute phase ago)
    if (it + 1 < 32) {
      int k0 = (it + 1) * 32;
      async_load16(Ag + k0,             &As[cur ^ 1][w][0][0]);
      async_load16(Ag + 64 * 1024 + k0, &As[cur ^ 1][w][64][0]);
      async_load16(Bg + k0,             &Bs[cur ^ 1][w][0][0]);
      async_load16(Bg + 64 * 1024 + k0, &Bs[cur ^ 1][w][64][0]);
    }
    bf16x8 af[4], bfr[4];
#pragma unroll
    for (int i = 0; i < 4; ++i)
      af[i] = *(const bf16x8*)&As[cur][quad][wm + i * 16 + q15][0];
#pragma unroll
    for (int j = 0; j < 4; ++j)
      bfr[j] = *(const bf16x8*)&Bs[cur][quad][wn + j * 16 + q15][0];
#pragma unroll
    for (int i = 0; i < 4; ++i)
#pragma unroll
      for (int j = 0; j < 4; ++j) acc[i][j] = mfma16(af[i], bfr[j], acc[i][j]);
  }

  if (vt && (n0 + wn) >= vt_col0) {
    // transposed store: acc[i][j][0..3] = 4 consecutive rows at one col
#pragma unroll
    for (int i = 0; i < 4; ++i) {
      int gm = m0 + wm + i * 16 + quad * 4;          // row (4 consecutive)
      int p = gm >> 10, mi = gm & 1023;
#pragma unroll
      for (int j = 0; j < 4; ++j) {
        int vchan = (n0 + wn - vt_col0) + j * 16 + q15;
        bf16x4 pk = {(__bf16)acc[i][j][0], (__bf16)acc[i][j][1],
                     (__bf16)acc[i][j][2], (__bf16)acc[i][j][3]};
        *(bf16x4*)&vt[((((size_t)p << 10) | vchan) << 10) | mi] = pk;
      }
    }
    return;
  }

#pragma unroll
  for (int i = 0; i < 4; ++i)
#pragma unroll
    for (int r = 0; r < 4; ++r) {
      int gm = m0 + wm + i * 16 + quad * 4 + r;
      size_t rowo = (size_t)gm * N + n0 + wn;
#pragma unroll
      for (int j = 0; j < 4; ++j) {
        int col = j * 16 + q15;
        float v = acc[i][j][r];
        if (Cf) {
          Cf[rowo + col] = v + (bias ? bias[n0 + wn + col] : 0.f);
        } else {
          if (addend) v += addend[rowo + col];
          Cb[rowo + col] = (__bf16)v;
        }
      }
    }
}

// ---------------------------------------------------------------------------
// Flash attention v2, S^T formulation. Block = (b,h,128 q rows), 4 waves.
// R9 changes: (1) Q fragments hoisted to registers (invariant across the 16
// kv-tiles -> saves 4 ds_read_b128/wave/tile); (2) PsB aliases the dead Qs
// region (LDS stays 48KB); (3) K/V staging double-buffered with cross-barrier
// prefetch, ONE barrier per kv-tile. No online softmax (logits bounded).
// XCD swizzle: all 8 q-tiles of a (b,h) land on one XCD.
__global__ __launch_bounds__(256) void attn_mfma(const bf16* __restrict__ qkvb,
                                                 const bf16* __restrict__ Vt,
                                                 bf16* __restrict__ attn_out) {
  __shared__ __align__(16) char smem[49152];
  bf16 (*Qs)[128][8] = (bf16(*)[128][8])smem;              // [8][128][8] 16KB
  bf16* PsB = (bf16*)smem;                                 // aliases Qs after prologue
  bf16 (*Ks)[8][64][8] = (bf16(*)[8][64][8])(smem + 16384); // [2][8][64][8] 16KB
  bf16 (*Vs)[8][64][8] = (bf16(*)[8][64][8])(smem + 32768); // [2][8][64][8] 16KB

  int t = threadIdx.x, w = t >> 6, lane = t & 63;
  int q15 = lane & 15, quad = lane >> 4;
  // swizzle: lid in [0,1024): xcd=lid&7, r=lid>>3; q-tile=r&7, bh=xcd+8*(r>>3)
  int lid = blockIdx.x + (blockIdx.y << 3);
  int xcd = lid & 7, rr = lid >> 3;
  int q0 = (rr & 7) * 128;
  int bh = xcd + ((rr >> 3) << 3);
  int b = bh >> 4, h = bh & 15;

  const bf16* Qg = qkvb + (size_t)(b * 1024 + q0) * 3072 + h * 64;
  const bf16* Kg = qkvb + (size_t)(b * 1024) * 3072 + 1024 + h * 64;
  const bf16* Vg = Vt + (size_t)(bh * 64) * 1024;

  // prologue: stage Q tile + K/V tile 0 (buffer 0)
#pragma unroll
  for (int cc = 0; cc < 2; ++cc) {
    int kc = w * 2 + cc;
    async_load16(Qg + (size_t)lane * 3072 + kc * 8,        &Qs[kc][0][0]);
    async_load16(Qg + (size_t)(64 + lane) * 3072 + kc * 8, &Qs[kc][64][0]);
  }
  {
    const bf16* Kg2 = Kg + (size_t)lane * 3072;
    const bf16* Vg2 = Vg + (size_t)lane * 1024;
    async_load16(Kg2 + (w * 2) * 8,     &Ks[0][w * 2][0][0]);
    async_load16(Kg2 + (w * 2 + 1) * 8, &Ks[0][w * 2 + 1][0][0]);
    async_load16(Vg2 + (w * 2) * 8,     &Vs[0][w * 2][0][0]);
    async_load16(Vg2 + (w * 2 + 1) * 8, &Vs[0][w * 2 + 1][0][0]);
  }
  __syncthreads();

  // hoist Q fragments (invariant over kv loop); lgkmcnt(0) before the loop's
  // first barrier guarantees reads complete before PsB overwrites Qs
  bf16x8 qfr[2][2];
#pragma unroll
  for (int ks = 0; ks < 2; ++ks)
#pragma unroll
    for (int nt = 0; nt < 2; ++nt)
      qfr[ks][nt] = *(const bf16x8*)&Qs[ks * 4 + quad][w * 32 + nt * 16 + q15][0];

  floatx4 oacc[4][2];
  float l_i[2] = {0.f, 0.f};
#pragma unroll
  for (int nt = 0; nt < 2; ++nt)
#pragma unroll
    for (int mt = 0; mt < 4; ++mt) oacc[mt][nt] = (floatx4){0.f, 0.f, 0.f, 0.f};

  for (int kt = 0; kt < 16; ++kt) {
    int cur = kt & 1;
    __syncthreads();   // drains prefetch(kt); at kt=0 also fences Qs->PsB reuse
    if (kt + 1 < 16) {
      int kv0n = (kt + 1) * 64;
      const bf16* Kg3 = Kg + (size_t)(kv0n + lane) * 3072;
      const bf16* Vg3 = Vg + (size_t)lane * 1024 + kv0n;
      async_load16(Kg3 + (w * 2) * 8,     &Ks[cur ^ 1][w * 2][0][0]);
      async_load16(Kg3 + (w * 2 + 1) * 8, &Ks[cur ^ 1][w * 2 + 1][0][0]);
      async_load16(Vg3 + (w * 2) * 8,     &Vs[cur ^ 1][w * 2][0][0]);
      async_load16(Vg3 + (w * 2 + 1) * 8, &Vs[cur ^ 1][w * 2 + 1][0][0]);
    }

    // S^T = K Q^T
    floatx4 sacc[4][2];
#pragma unroll
    for (int mt = 0; mt < 4; ++mt)
#pragma unroll
      for (int nt = 0; nt < 2; ++nt) sacc[mt][nt] = (floatx4){0.f, 0.f, 0.f, 0.f};
#pragma unroll
    for (int ks = 0; ks < 2; ++ks) {
      bf16x8 kf[4];
#pragma unroll
      for (int mt = 0; mt < 4; ++mt)
        kf[mt] = *(const bf16x8*)&Ks[cur][ks * 4 + quad][mt * 16 + q15][0];
#pragma unroll
      for (int mt = 0; mt < 4; ++mt)
#pragma unroll
        for (int nt = 0; nt < 2; ++nt)
          sacc[mt][nt] = mfma16(kf[mt], qfr[ks][nt], sacc[mt][nt]);
    }

    // softmax numerator: p = exp2(s) (no max/rescale; logits bounded)
#pragma unroll
    for (int nt = 0; nt < 2; ++nt) {
      float rsum = 0.f;
#pragma unroll
      for (int mt = 0; mt < 4; ++mt)
#pragma unroll
        for (int r = 0; r < 4; ++r) {
          float p = fexp2(sacc[mt][nt][r]);
          sacc[mt][nt][r] = p;
          rsum += p;
        }
      rsum += __shfl_xor(rsum, 16);
      rsum += __shfl_xor(rsum, 32);
      l_i[nt] += rsum;
    }

    // P^T -> per-wave LDS region (B-frag layout), same-wave RAW via lgkmcnt
#pragma unroll
    for (int nt = 0; nt < 2; ++nt)
#pragma unroll
      for (int mt = 0; mt < 4; ++mt) {
        bf16x4 pk = {(__bf16)sacc[mt][nt][0], (__bf16)sacc[mt][nt][1],
                     (__bf16)sacc[mt][nt][2], (__bf16)sacc[mt][nt][3]};
        int kc = mt * 2 + (quad >> 1);
        *(bf16x4*)&PsB[(size_t)(w * 2 + nt) * 1024 + kc * 128 + q15 * 8 + (quad & 1) * 4] = pk;
      }

    // O^T += V^T P^T
#pragma unroll
    for (int ks = 0; ks < 2; ++ks) {
      bf16x8 vf[4], pf[2];
#pragma unroll
      for (int mt = 0; mt < 4; ++mt)
        vf[mt] = *(const bf16x8*)&Vs[cur][ks * 4 + quad][mt * 16 + q15][0];
#pragma unroll
      for (int nt = 0; nt < 2; ++nt)
        pf[nt] = *(const bf16x8*)&PsB[(size_t)(w * 2 + nt) * 1024 + (ks * 4 + quad) * 128 + q15 * 8];
#pragma unroll
      for (int mt = 0; mt < 4; ++mt)
#pragma unroll
        for (int nt = 0; nt < 2; ++nt) oacc[mt][nt] = mfma16(vf[mt], pf[nt], oacc[mt][nt]);
    }
  }

  __syncthreads();
  bf16* T = (bf16*)smem + w * 2304;   // [32 q][72]; overlaps dead Qs/PsB + Ks head
#pragma unroll
  for (int nt = 0; nt < 2; ++nt) {
    float inv = 1.f / l_i[nt];
#pragma unroll
    for (int mt = 0; mt < 4; ++mt) {
      bf16x4 pk = {(__bf16)(oacc[mt][nt][0] * inv), (__bf16)(oacc[mt][nt][1] * inv),
                   (__bf16)(oacc[mt][nt][2] * inv), (__bf16)(oacc[mt][nt][3] * inv)};
      *(bf16x4*)&T[(nt * 16 + q15) * 72 + mt * 16 + quad * 4] = pk;
    }
  }
  __syncthreads();
  int row = lane >> 1, ch = (lane & 1) * 32;
  const bf16* Tr = T + row * 72 + ch;
  bf16* outp = attn_out + (size_t)(b * 1024 + q0 + w * 32 + row) * 1024 + h * 64 + ch;
#pragma unroll
  for (int i = 0; i < 4; ++i) *(bf16x8*)&outp[i * 8] = *(const bf16x8*)&Tr[i * 8];
}

// ---------------------------------------------------------------------------
extern "C" void kernel_launch(void* const* d_in, const int* in_sizes, int n_in,
                              void* d_out, int out_size, void* d_ws, size_t ws_size,
                              hipStream_t stream) {
  (void)in_sizes; (void)n_in; (void)out_size; (void)ws_size;
  const float* x       = (const float*)d_in[0];   // 8x1024x1024
  const float* W_qkv   = (const float*)d_in[1];   // 3072x1024
  const float* W_proj  = (const float*)d_in[2];   // 1024x1024
  const float* b_proj  = (const float*)d_in[3];   // 1024
  const float* coef_k  = (const float*)d_in[4];   // 10x3000
  const float* coef_v  = (const float*)d_in[5];   // 10x3000
  const int*   indices = (const int*)d_in[6];     // 10x3000
  const int*   task    = (const int*)d_in[7];     // scalar

  // Workspace (104 MB peak). attn_out aliases the dead S/S2b/Tt region.
  char* w8 = (char*)d_ws;
  float* Sf     = (float*)(w8);                  // 8MB  (2 fp32 planes, transient)
  bf16*  S2b    = (bf16*) (w8 + (8u  << 20));    // 4MB  [2048][1024] (transient)
  bf16*  Tt     = (bf16*) (w8 + (12u << 20));    // 4MB  [2][1024][1024] (transient)
  bf16*  Bmtb   = (bf16*) (w8 + (16u << 20));    // 2MB  (later reused for W_proj bf16)
  bf16*  Wcb    = (bf16*) (w8 + (18u << 20));    // 6MB  [3072][1024]
  bf16*  xb     = (bf16*) (w8 + (24u << 20));    // 16MB
  bf16*  qkvb   = (bf16*) (w8 + (40u << 20));    // 48MB [8192][3072]
  bf16*  Vt     = (bf16*) (w8 + (88u << 20));    // 16MB [128][64][1024]
  bf16*  attnout= (bf16*) (w8);                  // 16MB alias (Sf/S2b/Tt dead)

  const float QSCALE = 0.18033688011112042f;  // 0.125 * log2(e)

  dct_kernel<<<4096, 256, 0, stream>>>(Bmtb);

  // Dense S scatter (fp32), then convert to bf16 stacked planes
  hipMemsetAsync(Sf, 0, (size_t)8 << 20, stream);
  scatter_s<<<118, 256, 0, stream>>>(coef_k, coef_v, indices, task, Sf);
  conv_bf16<<<2048, 256, 0, stream>>>(Sf, S2b, 524288, 1.0f);

  // Wcb q band = W_qkv q band * QSCALE (scale folded into logits)
  conv_bf16<<<1024, 256, 0, stream>>>(W_qkv, Wcb, 262144, QSCALE);
  conv_bf16<<<8192, 256, 0, stream>>>(x, xb, 2097152, 1.0f);

  // LoRA: T = S @ Bm (stored transposed per plane), then both band GEMMs
  // W_band = Bm^T @ T_plane + W_qkv_band fused into one launch via grid.z
  gemm_bf16_nt<<<dim3(8, 16), 256, 0, stream>>>(S2b, Bmtb, nullptr, nullptr,
                                                nullptr, nullptr, Tt, 0, 1024);
  gemm_bf16_nt<<<dim3(8, 8, 2), 256, 0, stream>>>(Bmtb, Tt, Wcb + (1u << 20), nullptr,
                                                  W_qkv + (1u << 20), nullptr, nullptr,
                                                  1 << 30, 1024);

  // W_proj -> bf16 (into Bmtb slot, dead after the lora GEMMs)
  bf16* Wprojb = Bmtb;
  conv_bf16<<<1024, 256, 0, stream>>>(W_proj, Wprojb, 262144, 1.0f);

  // qkv = xb @ Wcb^T -> q,k bands bf16 into qkvb; v band transposed into Vt
  gemm_bf16_nt<<<dim3(24, 64), 256, 0, stream>>>(xb, Wcb, qkvb, nullptr,
                                                 nullptr, nullptr, Vt, 2048, 3072);

  // attention
  attn_mfma<<<dim3(8, 128), 256, 0, stream>>>(qkvb, Vt, attnout);

  // out = attn_out @ W_proj^T + b_proj  (fp32 out)
  gemm_bf16_nt<<<dim3(8, 64), 256, 0, stream>>>(attnout, Wprojb, nullptr, (float*)d_out,
                                                nullptr, b_proj, nullptr, 1 << 30, 1024);
}

// Round 11
// 390.220 us; speedup vs baseline: 1.2940x; 1.0049x over previous
//
#include <hip/hip_runtime.h>
#include <math.h>

// B=8, N=1024, C=1024, H=16, hd=64, n_tasks=10, n_frq=3000
#define NFRQ 3000

typedef __bf16 bf16;
typedef __attribute__((ext_vector_type(8))) __bf16 bf16x8;
typedef __attribute__((ext_vector_type(4))) __bf16 bf16x4;
typedef __attribute__((ext_vector_type(4))) float floatx4;

__device__ __forceinline__ floatx4 mfma16(bf16x8 a, bf16x8 b, floatx4 c) {
  return __builtin_amdgcn_mfma_f32_16x16x32_bf16(a, b, c, 0, 0, 0);
}

// async global->LDS, 16B per lane, dest = base + lane*16.
// NOTE (R10 post-mortem): nonzero imm offset arg produced NaN-corruption;
// keep offset=0 and do address math on the pointer.
__device__ __forceinline__ void async_load16(const bf16* g, bf16* l) {
  __builtin_amdgcn_global_load_lds(
      (const __attribute__((address_space(1))) unsigned int*)g,
      (__attribute__((address_space(3))) unsigned int*)l, 16, 0, 0);
}

__device__ __forceinline__ float fexp2(float x) {
  return __builtin_amdgcn_exp2f(x);
}

// ---------------------------------------------------------------------------
// Merged prep: DCT basis + 4 fp32->bf16 conversions in ONE launch.
// Block ranges: [0,1024) dct -> Bmtb ; [1024,2048) W_qkv q band *QSCALE ->
// Wcbq ; [2048,3072) W_proj -> Wprojb ; [3072,11264) x -> xb ;
// [11264,13312) Sf -> S2b (stream order guarantees scatter_s completed).
__global__ __launch_bounds__(256) void prep_kernel(
    const float* __restrict__ W_qkv, const float* __restrict__ W_proj,
    const float* __restrict__ x, const float* __restrict__ Sf,
    bf16* __restrict__ Bmtb, bf16* __restrict__ Wcbq,
    bf16* __restrict__ Wprojb, bf16* __restrict__ xb,
    bf16* __restrict__ S2b) {
  int r = blockIdx.x;
  if (r < 1024) {
    // DCT-II transposed bf16: out[t]=Bm[i][j] with j=t>>10,i=t&1023 (4/thread)
    int base = r * 1024 + (int)threadIdx.x * 4;
    const float cst = 0.04419417382415922f;  // sqrt(2)/32
    const float w = 1.5339807878856412e-3f;  // pi/2048
    bf16x4 o;
#pragma unroll
    for (int u = 0; u < 4; ++u) {
      int t = base + u;
      int j = t >> 10, i = t & 1023;
      int K = (i * (2 * j + 1)) & 4095;
      float v = (i == 0) ? 0.03125f : cst * __cosf((float)K * w);
      o[u] = (__bf16)v;
    }
    *(bf16x4*)&Bmtb[base] = o;
    return;
  }
  const float* src;
  bf16* dst;
  float scale = 1.0f;
  int i;
  if (r < 2048) {
    i = (r - 1024) * 256 + threadIdx.x;
    src = W_qkv; dst = Wcbq;
    scale = 0.18033688011112042f;  // 0.125 * log2(e)
  } else if (r < 3072) {
    i = (r - 2048) * 256 + threadIdx.x;
    src = W_proj; dst = Wprojb;
  } else if (r < 11264) {
    i = (r - 3072) * 256 + threadIdx.x;
    src = x; dst = xb;
  } else {
    i = (r - 11264) * 256 + threadIdx.x;
    src = Sf; dst = S2b;
  }
  float4 f = ((const float4*)src)[i];
  bf16x4 o = {(__bf16)(f.x * scale), (__bf16)(f.y * scale),
              (__bf16)(f.z * scale), (__bf16)(f.w * scale)};
  *(bf16x4*)&dst[(size_t)i * 4] = o;
}

// ---------------------------------------------------------------------------
// Dense scatter: S[id] += coef (2 fp32 planes, k and v). One thread per nz.
__global__ __launch_bounds__(256) void scatter_s(const float* __restrict__ coef_k,
                                                 const float* __restrict__ coef_v,
                                                 const int* __restrict__ idx,
                                                 const int* __restrict__ task,
                                                 float* __restrict__ S) {
  int nz = blockIdx.x * 256 + threadIdx.x;
  if (nz >= 10 * NFRQ || nz >= (*task + 1) * NFRQ) return;
  int id = idx[nz];
  atomicAdd(S + id, coef_k[nz]);
  atomicAdd(S + (1u << 20) + id, coef_v[nz]);
}

// ---------------------------------------------------------------------------
// MFMA NT GEMM: C[m][n] = sum_k A[m][k]*B[n][k], K=1024 fixed, ldc=N.
// 128x128 block tile, 4 waves each 64x64 (4x4 of 16x16x32), BK=32,
// LDS double-buffer, cross-barrier prefetch, XCD-band swizzle (R9 verbatim —
// the R10 imm-offset variant corrupted data; see async_load16 note).
// blockIdx.z: plane offset of 1M elements applied to B/Cb/addend.
// Output: Cf!=null -> fp32 (+bias); else bf16 (+= addend fp32 if !=null).
// If vt!=null: tiles with col>=vt_col0 stored TRANSPOSED into
// vt[((p<<10)|vchan)<<10 | m] (p=row>>10, m=row&1023, vchan=col-vt_col0).
__global__ __launch_bounds__(256) void gemm_bf16_nt(const bf16* __restrict__ A,
                                                    const bf16* __restrict__ B,
                                                    bf16* __restrict__ Cb,
                                                    float* __restrict__ Cf,
                                                    const float* __restrict__ addend,
                                                    const float* __restrict__ bias,
                                                    bf16* __restrict__ vt,
                                                    int vt_col0,
                                                    int N) {
  __shared__ bf16 As[2][4][128][8];   // 16KB (double buffer)
  __shared__ bf16 Bs[2][4][128][8];   // 16KB
  size_t zoff = (size_t)blockIdx.z << 20;
  B += zoff;
  if (Cb) Cb += zoff;
  if (addend) addend += zoff;
  int t = threadIdx.x, w = t >> 6, lane = t & 63;
  int q15 = lane & 15, quad = lane >> 4;
  // XCD swizzle (bijective remap of the block grid; gridDim.y % 8 == 0)
  int lid = blockIdx.x + gridDim.x * blockIdx.y;
  int band = gridDim.y >> 3;
  int xcd = lid & 7, tt = lid >> 3;
  int by = xcd * band + tt % band;
  int bx = tt / band;
  int m0 = by * 128, n0 = bx * 128;
  int wm = (w >> 1) * 64, wn = (w & 1) * 64;
  floatx4 acc[4][4];
#pragma unroll
  for (int i = 0; i < 4; ++i)
#pragma unroll
    for (int j = 0; j < 4; ++j) acc[i][j] = (floatx4){0.f, 0.f, 0.f, 0.f};

  const bf16* Ag = A + (size_t)(m0 + lane) * 1024 + w * 8;
  const bf16* Bg = B + (size_t)(n0 + lane) * 1024 + w * 8;

  // prologue: stage K-step 0 into buffer 0
  async_load16(Ag,             &As[0][w][0][0]);
  async_load16(Ag + 64 * 1024, &As[0][w][64][0]);
  async_load16(Bg,             &Bs[0][w][0][0]);
  async_load16(Bg + 64 * 1024, &Bs[0][w][64][0]);

  for (int it = 0; it < 32; ++it) {
    int cur = it & 1;
    __syncthreads();   // drains loads(it) (issued one full compute phase ago)
    if (it + 1 < 32) {
      int k0 = (it + 1) * 32;
      async_load16(Ag + k0,             &As[cur ^ 1][w][0][0]);
      async_load16(Ag + 64 * 1024 + k0, &As[cur ^ 1][w][64][0]);
      async_load16(Bg + k0,             &Bs[cur ^ 1][w][0][0]);
      async_load16(Bg + 64 * 1024 + k0, &Bs[cur ^ 1][w][64][0]);
    }
    bf16x8 af[4], bfr[4];
#pragma unroll
    for (int i = 0; i < 4; ++i)
      af[i] = *(const bf16x8*)&As[cur][quad][wm + i * 16 + q15][0];
#pragma unroll
    for (int j = 0; j < 4; ++j)
      bfr[j] = *(const bf16x8*)&Bs[cur][quad][wn + j * 16 + q15][0];
#pragma unroll
    for (int i = 0; i < 4; ++i)
#pragma unroll
      for (int j = 0; j < 4; ++j) acc[i][j] = mfma16(af[i], bfr[j], acc[i][j]);
  }

  if (vt && (n0 + wn) >= vt_col0) {
    // transposed store: acc[i][j][0..3] = 4 consecutive rows at one col
#pragma unroll
    for (int i = 0; i < 4; ++i) {
      int gm = m0 + wm + i * 16 + quad * 4;          // row (4 consecutive)
      int p = gm >> 10, mi = gm & 1023;
#pragma unroll
      for (int j = 0; j < 4; ++j) {
        int vchan = (n0 + wn - vt_col0) + j * 16 + q15;
        bf16x4 pk = {(__bf16)acc[i][j][0], (__bf16)acc[i][j][1],
                     (__bf16)acc[i][j][2], (__bf16)acc[i][j][3]};
        *(bf16x4*)&vt[((((size_t)p << 10) | vchan) << 10) | mi] = pk;
      }
    }
    return;
  }

#pragma unroll
  for (int i = 0; i < 4; ++i)
#pragma unroll
    for (int r = 0; r < 4; ++r) {
      int gm = m0 + wm + i * 16 + quad * 4 + r;
      size_t rowo = (size_t)gm * N + n0 + wn;
#pragma unroll
      for (int j = 0; j < 4; ++j) {
        int col = j * 16 + q15;
        float v = acc[i][j][r];
        if (Cf) {
          Cf[rowo + col] = v + (bias ? bias[n0 + wn + col] : 0.f);
        } else {
          if (addend) v += addend[rowo + col];
          Cb[rowo + col] = (__bf16)v;
        }
      }
    }
}

// ---------------------------------------------------------------------------
// Flash attention, S^T formulation (R9 structure). Block = (b,h,128 q rows),
// 4 waves. Q fragments in registers; PsB aliases dead Qs; K/V double-buffered
// with cross-barrier prefetch, one barrier per kv-tile. No online softmax
// (logits pre-scaled by 0.125*log2e, bounded). XCD swizzle keeps a (b,h)'s
// q-tiles on one XCD.
__global__ __launch_bounds__(256) void attn_mfma(const bf16* __restrict__ qkvb,
                                                 const bf16* __restrict__ Vt,
                                                 bf16* __restrict__ attn_out) {
  __shared__ __align__(16) char smem[49152];
  bf16 (*Qs)[128][8] = (bf16(*)[128][8])smem;              // [8][128][8] 16KB
  bf16* PsB = (bf16*)smem;                                 // aliases Qs after prologue
  bf16 (*Ks)[8][64][8] = (bf16(*)[8][64][8])(smem + 16384); // [2][8][64][8] 16KB
  bf16 (*Vs)[8][64][8] = (bf16(*)[8][64][8])(smem + 32768); // [2][8][64][8] 16KB

  int t = threadIdx.x, w = t >> 6, lane = t & 63;
  int q15 = lane & 15, quad = lane >> 4;
  int lid = blockIdx.x + (blockIdx.y << 3);
  int xcd = lid & 7, rr = lid >> 3;
  int q0 = (rr & 7) * 128;
  int bh = xcd + ((rr >> 3) << 3);
  int b = bh >> 4, h = bh & 15;

  const bf16* Qg = qkvb + (size_t)(b * 1024 + q0) * 3072 + h * 64;
  const bf16* Kg = qkvb + (size_t)(b * 1024) * 3072 + 1024 + h * 64;
  const bf16* Vg = Vt + (size_t)(bh * 64) * 1024;

  // prologue: stage Q tile + K/V tile 0 (buffer 0)
#pragma unroll
  for (int cc = 0; cc < 2; ++cc) {
    int kc = w * 2 + cc;
    async_load16(Qg + (size_t)lane * 3072 + kc * 8,        &Qs[kc][0][0]);
    async_load16(Qg + (size_t)(64 + lane) * 3072 + kc * 8, &Qs[kc][64][0]);
  }
  {
    const bf16* Kg2 = Kg + (size_t)lane * 3072;
    const bf16* Vg2 = Vg + (size_t)lane * 1024;
    async_load16(Kg2 + (w * 2) * 8,     &Ks[0][w * 2][0][0]);
    async_load16(Kg2 + (w * 2 + 1) * 8, &Ks[0][w * 2 + 1][0][0]);
    async_load16(Vg2 + (w * 2) * 8,     &Vs[0][w * 2][0][0]);
    async_load16(Vg2 + (w * 2 + 1) * 8, &Vs[0][w * 2 + 1][0][0]);
  }
  __syncthreads();

  // hoist Q fragments (invariant over kv loop)
  bf16x8 qfr[2][2];
#pragma unroll
  for (int ks = 0; ks < 2; ++ks)
#pragma unroll
    for (int nt = 0; nt < 2; ++nt)
      qfr[ks][nt] = *(const bf16x8*)&Qs[ks * 4 + quad][w * 32 + nt * 16 + q15][0];

  floatx4 oacc[4][2];
  float l_i[2] = {0.f, 0.f};
#pragma unroll
  for (int nt = 0; nt < 2; ++nt)
#pragma unroll
    for (int mt = 0; mt < 4; ++mt) oacc[mt][nt] = (floatx4){0.f, 0.f, 0.f, 0.f};

  for (int kt = 0; kt < 16; ++kt) {
    int cur = kt & 1;
    __syncthreads();   // drains prefetch(kt); at kt=0 also fences Qs->PsB reuse
    if (kt + 1 < 16) {
      int kv0n = (kt + 1) * 64;
      const bf16* Kg3 = Kg + (size_t)(kv0n + lane) * 3072;
      const bf16* Vg3 = Vg + (size_t)lane * 1024 + kv0n;
      async_load16(Kg3 + (w * 2) * 8,     &Ks[cur ^ 1][w * 2][0][0]);
      async_load16(Kg3 + (w * 2 + 1) * 8, &Ks[cur ^ 1][w * 2 + 1][0][0]);
      async_load16(Vg3 + (w * 2) * 8,     &Vs[cur ^ 1][w * 2][0][0]);
      async_load16(Vg3 + (w * 2 + 1) * 8, &Vs[cur ^ 1][w * 2 + 1][0][0]);
    }

    // S^T = K Q^T
    floatx4 sacc[4][2];
#pragma unroll
    for (int mt = 0; mt < 4; ++mt)
#pragma unroll
      for (int nt = 0; nt < 2; ++nt) sacc[mt][nt] = (floatx4){0.f, 0.f, 0.f, 0.f};
#pragma unroll
    for (int ks = 0; ks < 2; ++ks) {
      bf16x8 kf[4];
#pragma unroll
      for (int mt = 0; mt < 4; ++mt)
        kf[mt] = *(const bf16x8*)&Ks[cur][ks * 4 + quad][mt * 16 + q15][0];
#pragma unroll
      for (int mt = 0; mt < 4; ++mt)
#pragma unroll
        for (int nt = 0; nt < 2; ++nt)
          sacc[mt][nt] = mfma16(kf[mt], qfr[ks][nt], sacc[mt][nt]);
    }

    // softmax numerator: p = exp2(s) (no max/rescale; logits bounded)
#pragma unroll
    for (int nt = 0; nt < 2; ++nt) {
      float rsum = 0.f;
#pragma unroll
      for (int mt = 0; mt < 4; ++mt)
#pragma unroll
        for (int r = 0; r < 4; ++r) {
          float p = fexp2(sacc[mt][nt][r]);
          sacc[mt][nt][r] = p;
          rsum += p;
        }
      rsum += __shfl_xor(rsum, 16);
      rsum += __shfl_xor(rsum, 32);
      l_i[nt] += rsum;
    }

    // P^T -> per-wave LDS region (B-frag layout), same-wave RAW via lgkmcnt
#pragma unroll
    for (int nt = 0; nt < 2; ++nt)
#pragma unroll
      for (int mt = 0; mt < 4; ++mt) {
        bf16x4 pk = {(__bf16)sacc[mt][nt][0], (__bf16)sacc[mt][nt][1],
                     (__bf16)sacc[mt][nt][2], (__bf16)sacc[mt][nt][3]};
        int kc = mt * 2 + (quad >> 1);
        *(bf16x4*)&PsB[(size_t)(w * 2 + nt) * 1024 + kc * 128 + q15 * 8 + (quad & 1) * 4] = pk;
      }

    // O^T += V^T P^T
#pragma unroll
    for (int ks = 0; ks < 2; ++ks) {
      bf16x8 vf[4], pf[2];
#pragma unroll
      for (int mt = 0; mt < 4; ++mt)
        vf[mt] = *(const bf16x8*)&Vs[cur][ks * 4 + quad][mt * 16 + q15][0];
#pragma unroll
      for (int nt = 0; nt < 2; ++nt)
        pf[nt] = *(const bf16x8*)&PsB[(size_t)(w * 2 + nt) * 1024 + (ks * 4 + quad) * 128 + q15 * 8];
#pragma unroll
      for (int mt = 0; mt < 4; ++mt)
#pragma unroll
        for (int nt = 0; nt < 2; ++nt) oacc[mt][nt] = mfma16(vf[mt], pf[nt], oacc[mt][nt]);
    }
  }

  __syncthreads();
  bf16* T = (bf16*)smem + w * 2304;   // [32 q][72]; overlaps dead Qs/PsB + Ks head
#pragma unroll
  for (int nt = 0; nt < 2; ++nt) {
    float inv = 1.f / l_i[nt];
#pragma unroll
    for (int mt = 0; mt < 4; ++mt) {
      bf16x4 pk = {(__bf16)(oacc[mt][nt][0] * inv), (__bf16)(oacc[mt][nt][1] * inv),
                   (__bf16)(oacc[mt][nt][2] * inv), (__bf16)(oacc[mt][nt][3] * inv)};
      *(bf16x4*)&T[(nt * 16 + q15) * 72 + mt * 16 + quad * 4] = pk;
    }
  }
  __syncthreads();
  int row = lane >> 1, ch = (lane & 1) * 32;
  const bf16* Tr = T + row * 72 + ch;
  bf16* outp = attn_out + (size_t)(b * 1024 + q0 + w * 32 + row) * 1024 + h * 64 + ch;
#pragma unroll
  for (int i = 0; i < 4; ++i) *(bf16x8*)&outp[i * 8] = *(const bf16x8*)&Tr[i * 8];
}

// ---------------------------------------------------------------------------
extern "C" void kernel_launch(void* const* d_in, const int* in_sizes, int n_in,
                              void* d_out, int out_size, void* d_ws, size_t ws_size,
                              hipStream_t stream) {
  (void)in_sizes; (void)n_in; (void)out_size; (void)ws_size;
  const float* x       = (const float*)d_in[0];   // 8x1024x1024
  const float* W_qkv   = (const float*)d_in[1];   // 3072x1024
  const float* W_proj  = (const float*)d_in[2];   // 1024x1024
  const float* b_proj  = (const float*)d_in[3];   // 1024
  const float* coef_k  = (const float*)d_in[4];   // 10x3000
  const float* coef_v  = (const float*)d_in[5];   // 10x3000
  const int*   indices = (const int*)d_in[6];     // 10x3000
  const int*   task    = (const int*)d_in[7];     // scalar

  // Workspace (106 MB peak). attn_out aliases the dead Sf/S2b/Tt region.
  char* w8 = (char*)d_ws;
  float* Sf     = (float*)(w8);                   // 8MB  (2 fp32 planes, transient)
  bf16*  S2b    = (bf16*) (w8 + (8u  << 20));     // 4MB  [2048][1024] (transient)
  bf16*  Tt     = (bf16*) (w8 + (12u << 20));     // 4MB  [2][1024][1024] (transient)
  bf16*  Bmtb   = (bf16*) (w8 + (16u << 20));     // 2MB
  bf16*  Wcb    = (bf16*) (w8 + (18u << 20));     // 6MB  [3072][1024]
  bf16*  xb     = (bf16*) (w8 + (24u << 20));     // 16MB
  bf16*  qkvb   = (bf16*) (w8 + (40u << 20));     // 48MB [8192][3072]
  bf16*  Vt     = (bf16*) (w8 + (88u << 20));     // 16MB [128][64][1024]
  bf16*  Wprojb = (bf16*) (w8 + (104u << 20));    // 2MB
  bf16*  attnout= (bf16*) (w8);                   // 16MB alias (Sf/S2b/Tt dead)

  // Dense S scatter (fp32 planes), then ONE merged prep launch
  hipMemsetAsync(Sf, 0, (size_t)8 << 20, stream);
  scatter_s<<<118, 256, 0, stream>>>(coef_k, coef_v, indices, task, Sf);
  prep_kernel<<<13312, 256, 0, stream>>>(W_qkv, W_proj, x, Sf,
                                         Bmtb, Wcb, Wprojb, xb, S2b);

  // LoRA: T = S @ Bm (stored transposed per plane), then both band GEMMs
  // W_band = Bm^T @ T_plane + W_qkv_band fused into one launch via grid.z
  gemm_bf16_nt<<<dim3(8, 16), 256, 0, stream>>>(S2b, Bmtb, nullptr, nullptr,
                                                nullptr, nullptr, Tt, 0, 1024);
  gemm_bf16_nt<<<dim3(8, 8, 2), 256, 0, stream>>>(Bmtb, Tt, Wcb + (1u << 20), nullptr,
                                                  W_qkv + (1u << 20), nullptr, nullptr,
                                                  1 << 30, 1024);

  // qkv = xb @ Wcb^T -> q,k bands bf16 into qkvb; v band transposed into Vt
  gemm_bf16_nt<<<dim3(24, 64), 256, 0, stream>>>(xb, Wcb, qkvb, nullptr,
                                                 nullptr, nullptr, Vt, 2048, 3072);

  // attention
  attn_mfma<<<dim3(8, 128), 256, 0, stream>>>(qkvb, Vt, attnout);

  // out = attn_out @ W_proj^T + b_proj  (fp32 out)
  gemm_bf16_nt<<<dim3(8, 64), 256, 0, stream>>>(attnout, Wprojb, nullptr, (float*)d_out,
                                                nullptr, b_proj, nullptr, 1 << 30, 1024);
}

// Round 12
// 374.395 us; speedup vs baseline: 1.3487x; 1.0423x over previous
//
#include <hip/hip_runtime.h>
#include <math.h>

// B=8, N=1024, C=1024, H=16, hd=64, n_tasks=10, n_frq=3000
#define NFRQ 3000

typedef __bf16 bf16;
typedef __attribute__((ext_vector_type(8))) __bf16 bf16x8;
typedef __attribute__((ext_vector_type(4))) __bf16 bf16x4;
typedef __attribute__((ext_vector_type(4))) float floatx4;

__device__ __forceinline__ floatx4 mfma16(bf16x8 a, bf16x8 b, floatx4 c) {
  return __builtin_amdgcn_mfma_f32_16x16x32_bf16(a, b, c, 0, 0, 0);
}

// async global->LDS, 16B per lane, dest = base + lane*16.
// NOTE (R10 post-mortem): nonzero imm offset arg produced NaN-corruption;
// keep offset=0 and do address math on the pointer.
__device__ __forceinline__ void async_load16(const bf16* g, bf16* l) {
  __builtin_amdgcn_global_load_lds(
      (const __attribute__((address_space(1))) unsigned int*)g,
      (__attribute__((address_space(3))) unsigned int*)l, 16, 0, 0);
}

__device__ __forceinline__ float fexp2(float x) {
  return __builtin_amdgcn_exp2f(x);
}

// ---------------------------------------------------------------------------
// Merged prep: DCT basis + 4 fp32->bf16 conversions in ONE launch.
// Block ranges: [0,1024) dct -> Bmtb ; [1024,2048) W_qkv q band *QSCALE ->
// Wcbq ; [2048,3072) W_proj -> Wprojb ; [3072,11264) x -> xb ;
// [11264,13312) Sf -> S2b (stream order guarantees scatter_s completed).
__global__ __launch_bounds__(256) void prep_kernel(
    const float* __restrict__ W_qkv, const float* __restrict__ W_proj,
    const float* __restrict__ x, const float* __restrict__ Sf,
    bf16* __restrict__ Bmtb, bf16* __restrict__ Wcbq,
    bf16* __restrict__ Wprojb, bf16* __restrict__ xb,
    bf16* __restrict__ S2b) {
  int r = blockIdx.x;
  if (r < 1024) {
    // DCT-II transposed bf16: out[t]=Bm[i][j] with j=t>>10,i=t&1023 (4/thread)
    int base = r * 1024 + (int)threadIdx.x * 4;
    const float cst = 0.04419417382415922f;  // sqrt(2)/32
    const float w = 1.5339807878856412e-3f;  // pi/2048
    bf16x4 o;
#pragma unroll
    for (int u = 0; u < 4; ++u) {
      int t = base + u;
      int j = t >> 10, i = t & 1023;
      int K = (i * (2 * j + 1)) & 4095;
      float v = (i == 0) ? 0.03125f : cst * __cosf((float)K * w);
      o[u] = (__bf16)v;
    }
    *(bf16x4*)&Bmtb[base] = o;
    return;
  }
  const float* src;
  bf16* dst;
  float scale = 1.0f;
  int i;
  if (r < 2048) {
    i = (r - 1024) * 256 + threadIdx.x;
    src = W_qkv; dst = Wcbq;
    scale = 0.18033688011112042f;  // 0.125 * log2(e)
  } else if (r < 3072) {
    i = (r - 2048) * 256 + threadIdx.x;
    src = W_proj; dst = Wprojb;
  } else if (r < 11264) {
    i = (r - 3072) * 256 + threadIdx.x;
    src = x; dst = xb;
  } else {
    i = (r - 11264) * 256 + threadIdx.x;
    src = Sf; dst = S2b;
  }
  float4 f = ((const float4*)src)[i];
  bf16x4 o = {(__bf16)(f.x * scale), (__bf16)(f.y * scale),
              (__bf16)(f.z * scale), (__bf16)(f.w * scale)};
  *(bf16x4*)&dst[(size_t)i * 4] = o;
}

// ---------------------------------------------------------------------------
// Dense scatter: S[id] += coef (2 fp32 planes, k and v). One thread per nz.
__global__ __launch_bounds__(256) void scatter_s(const float* __restrict__ coef_k,
                                                 const float* __restrict__ coef_v,
                                                 const int* __restrict__ idx,
                                                 const int* __restrict__ task,
                                                 float* __restrict__ S) {
  int nz = blockIdx.x * 256 + threadIdx.x;
  if (nz >= 10 * NFRQ || nz >= (*task + 1) * NFRQ) return;
  int id = idx[nz];
  atomicAdd(S + id, coef_k[nz]);
  atomicAdd(S + (1u << 20) + id, coef_v[nz]);
}

// ---------------------------------------------------------------------------
// MFMA NT GEMM, 128x128 block tile (R11 verbatim; used for the big qkv GEMM).
// 4 waves each 64x64 (4x4 of 16x16x32), BK=32, LDS double-buffer,
// cross-barrier prefetch, XCD-band swizzle.
// blockIdx.z: plane offset of 1M elements applied to B/Cb/addend.
// Output: Cf!=null -> fp32 (+bias); else bf16 (+= addend fp32 if !=null).
// If vt!=null: tiles with col>=vt_col0 stored TRANSPOSED into
// vt[((p<<10)|vchan)<<10 | m] (p=row>>10, m=row&1023, vchan=col-vt_col0).
__global__ __launch_bounds__(256) void gemm_bf16_nt(const bf16* __restrict__ A,
                                                    const bf16* __restrict__ B,
                                                    bf16* __restrict__ Cb,
                                                    float* __restrict__ Cf,
                                                    const float* __restrict__ addend,
                                                    const float* __restrict__ bias,
                                                    bf16* __restrict__ vt,
                                                    int vt_col0,
                                                    int N) {
  __shared__ bf16 As[2][4][128][8];   // 16KB (double buffer)
  __shared__ bf16 Bs[2][4][128][8];   // 16KB
  size_t zoff = (size_t)blockIdx.z << 20;
  B += zoff;
  if (Cb) Cb += zoff;
  if (addend) addend += zoff;
  int t = threadIdx.x, w = t >> 6, lane = t & 63;
  int q15 = lane & 15, quad = lane >> 4;
  // XCD swizzle (bijective remap of the block grid; gridDim.y % 8 == 0)
  int lid = blockIdx.x + gridDim.x * blockIdx.y;
  int band = gridDim.y >> 3;
  int xcd = lid & 7, tt = lid >> 3;
  int by = xcd * band + tt % band;
  int bx = tt / band;
  int m0 = by * 128, n0 = bx * 128;
  int wm = (w >> 1) * 64, wn = (w & 1) * 64;
  floatx4 acc[4][4];
#pragma unroll
  for (int i = 0; i < 4; ++i)
#pragma unroll
    for (int j = 0; j < 4; ++j) acc[i][j] = (floatx4){0.f, 0.f, 0.f, 0.f};

  const bf16* Ag = A + (size_t)(m0 + lane) * 1024 + w * 8;
  const bf16* Bg = B + (size_t)(n0 + lane) * 1024 + w * 8;

  // prologue: stage K-step 0 into buffer 0
  async_load16(Ag,             &As[0][w][0][0]);
  async_load16(Ag + 64 * 1024, &As[0][w][64][0]);
  async_load16(Bg,             &Bs[0][w][0][0]);
  async_load16(Bg + 64 * 1024, &Bs[0][w][64][0]);

  for (int it = 0; it < 32; ++it) {
    int cur = it & 1;
    __syncthreads();   // drains loads(it) (issued one full compute phase ago)
    if (it + 1 < 32) {
      int k0 = (it + 1) * 32;
      async_load16(Ag + k0,             &As[cur ^ 1][w][0][0]);
      async_load16(Ag + 64 * 1024 + k0, &As[cur ^ 1][w][64][0]);
      async_load16(Bg + k0,             &Bs[cur ^ 1][w][0][0]);
      async_load16(Bg + 64 * 1024 + k0, &Bs[cur ^ 1][w][64][0]);
    }
    bf16x8 af[4], bfr[4];
#pragma unroll
    for (int i = 0; i < 4; ++i)
      af[i] = *(const bf16x8*)&As[cur][quad][wm + i * 16 + q15][0];
#pragma unroll
    for (int j = 0; j < 4; ++j)
      bfr[j] = *(const bf16x8*)&Bs[cur][quad][wn + j * 16 + q15][0];
#pragma unroll
    for (int i = 0; i < 4; ++i)
#pragma unroll
      for (int j = 0; j < 4; ++j) acc[i][j] = mfma16(af[i], bfr[j], acc[i][j]);
  }

  if (vt && (n0 + wn) >= vt_col0) {
    // transposed store: acc[i][j][0..3] = 4 consecutive rows at one col
#pragma unroll
    for (int i = 0; i < 4; ++i) {
      int gm = m0 + wm + i * 16 + quad * 4;          // row (4 consecutive)
      int p = gm >> 10, mi = gm & 1023;
#pragma unroll
      for (int j = 0; j < 4; ++j) {
        int vchan = (n0 + wn - vt_col0) + j * 16 + q15;
        bf16x4 pk = {(__bf16)acc[i][j][0], (__bf16)acc[i][j][1],
                     (__bf16)acc[i][j][2], (__bf16)acc[i][j][3]};
        *(bf16x4*)&vt[((((size_t)p << 10) | vchan) << 10) | mi] = pk;
      }
    }
    return;
  }

#pragma unroll
  for (int i = 0; i < 4; ++i)
#pragma unroll
    for (int r = 0; r < 4; ++r) {
      int gm = m0 + wm + i * 16 + quad * 4 + r;
      size_t rowo = (size_t)gm * N + n0 + wn;
#pragma unroll
      for (int j = 0; j < 4; ++j) {
        int col = j * 16 + q15;
        float v = acc[i][j][r];
        if (Cf) {
          Cf[rowo + col] = v + (bias ? bias[n0 + wn + col] : 0.f);
        } else {
          if (addend) v += addend[rowo + col];
          Cb[rowo + col] = (__bf16)v;
        }
      }
    }
}

// ---------------------------------------------------------------------------
// MFMA NT GEMM, 64x64 block tile — for SMALL GEMMs (lora1, lora2, proj).
// The 128-tile kernel at grid 128-512 blocks leaves the machine idle
// (0.5-2 blocks/CU, pure latency exposure); 64-tiles quadruple the block
// count (2-8/CU) so co-resident blocks hide each other's stalls. Per wave:
// one 32x32 quadrant (2x2 16x16x32 frags), 1 A + 1 B staging inst per
// K-step, same dbuf/prefetch/swizzle structure. Same epilogue variants.
__global__ __launch_bounds__(256) void gemm64_bf16_nt(const bf16* __restrict__ A,
                                                      const bf16* __restrict__ B,
                                                      bf16* __restrict__ Cb,
                                                      float* __restrict__ Cf,
                                                      const float* __restrict__ addend,
                                                      const float* __restrict__ bias,
                                                      bf16* __restrict__ vt,
                                                      int vt_col0,
                                                      int N) {
  __shared__ bf16 As[2][4][64][8];   // 8KB (double buffer)
  __shared__ bf16 Bs[2][4][64][8];   // 8KB
  size_t zoff = (size_t)blockIdx.z << 20;
  B += zoff;
  if (Cb) Cb += zoff;
  if (addend) addend += zoff;
  int t = threadIdx.x, w = t >> 6, lane = t & 63;
  int q15 = lane & 15, quad = lane >> 4;
  // XCD swizzle (bijective; gridDim.y % 8 == 0 for all our grids)
  int lid = blockIdx.x + gridDim.x * blockIdx.y;
  int band = gridDim.y >> 3;
  int xcd = lid & 7, tt = lid >> 3;
  int by = xcd * band + tt % band;
  int bx = tt / band;
  int m0 = by * 64, n0 = bx * 64;
  int wm = (w >> 1) * 32, wn = (w & 1) * 32;
  floatx4 acc[2][2];
#pragma unroll
  for (int i = 0; i < 2; ++i)
#pragma unroll
    for (int j = 0; j < 2; ++j) acc[i][j] = (floatx4){0.f, 0.f, 0.f, 0.f};

  const bf16* Ag = A + (size_t)(m0 + lane) * 1024 + w * 8;
  const bf16* Bg = B + (size_t)(n0 + lane) * 1024 + w * 8;

  // prologue: stage K-step 0 into buffer 0 (wave w stages kchunk w, 64 rows)
  async_load16(Ag, &As[0][w][0][0]);
  async_load16(Bg, &Bs[0][w][0][0]);

  for (int it = 0; it < 32; ++it) {
    int cur = it & 1;
    __syncthreads();   // drains loads(it)
    if (it + 1 < 32) {
      int k0 = (it + 1) * 32;
      async_load16(Ag + k0, &As[cur ^ 1][w][0][0]);
      async_load16(Bg + k0, &Bs[cur ^ 1][w][0][0]);
    }
    bf16x8 af[2], bfr[2];
#pragma unroll
    for (int i = 0; i < 2; ++i)
      af[i] = *(const bf16x8*)&As[cur][quad][wm + i * 16 + q15][0];
#pragma unroll
    for (int j = 0; j < 2; ++j)
      bfr[j] = *(const bf16x8*)&Bs[cur][quad][wn + j * 16 + q15][0];
#pragma unroll
    for (int i = 0; i < 2; ++i)
#pragma unroll
      for (int j = 0; j < 2; ++j) acc[i][j] = mfma16(af[i], bfr[j], acc[i][j]);
  }

  if (vt && (n0 + wn) >= vt_col0) {
#pragma unroll
    for (int i = 0; i < 2; ++i) {
      int gm = m0 + wm + i * 16 + quad * 4;          // row (4 consecutive)
      int p = gm >> 10, mi = gm & 1023;
#pragma unroll
      for (int j = 0; j < 2; ++j) {
        int vchan = (n0 + wn - vt_col0) + j * 16 + q15;
        bf16x4 pk = {(__bf16)acc[i][j][0], (__bf16)acc[i][j][1],
                     (__bf16)acc[i][j][2], (__bf16)acc[i][j][3]};
        *(bf16x4*)&vt[((((size_t)p << 10) | vchan) << 10) | mi] = pk;
      }
    }
    return;
  }

#pragma unroll
  for (int i = 0; i < 2; ++i)
#pragma unroll
    for (int r = 0; r < 4; ++r) {
      int gm = m0 + wm + i * 16 + quad * 4 + r;
      size_t rowo = (size_t)gm * N + n0 + wn;
#pragma unroll
      for (int j = 0; j < 2; ++j) {
        int col = j * 16 + q15;
        float v = acc[i][j][r];
        if (Cf) {
          Cf[rowo + col] = v + (bias ? bias[n0 + wn + col] : 0.f);
        } else {
          if (addend) v += addend[rowo + col];
          Cb[rowo + col] = (__bf16)v;
        }
      }
    }
}

// ---------------------------------------------------------------------------
// Flash attention, S^T formulation (R9 structure). Block = (b,h,128 q rows),
// 4 waves. Q fragments in registers; PsB aliases dead Qs; K/V double-buffered
// with cross-barrier prefetch, one barrier per kv-tile. No online softmax
// (logits pre-scaled by 0.125*log2e, bounded). XCD swizzle keeps a (b,h)'s
// q-tiles on one XCD.
__global__ __launch_bounds__(256) void attn_mfma(const bf16* __restrict__ qkvb,
                                                 const bf16* __restrict__ Vt,
                                                 bf16* __restrict__ attn_out) {
  __shared__ __align__(16) char smem[49152];
  bf16 (*Qs)[128][8] = (bf16(*)[128][8])smem;              // [8][128][8] 16KB
  bf16* PsB = (bf16*)smem;                                 // aliases Qs after prologue
  bf16 (*Ks)[8][64][8] = (bf16(*)[8][64][8])(smem + 16384); // [2][8][64][8] 16KB
  bf16 (*Vs)[8][64][8] = (bf16(*)[8][64][8])(smem + 32768); // [2][8][64][8] 16KB

  int t = threadIdx.x, w = t >> 6, lane = t & 63;
  int q15 = lane & 15, quad = lane >> 4;
  int lid = blockIdx.x + (blockIdx.y << 3);
  int xcd = lid & 7, rr = lid >> 3;
  int q0 = (rr & 7) * 128;
  int bh = xcd + ((rr >> 3) << 3);
  int b = bh >> 4, h = bh & 15;

  const bf16* Qg = qkvb + (size_t)(b * 1024 + q0) * 3072 + h * 64;
  const bf16* Kg = qkvb + (size_t)(b * 1024) * 3072 + 1024 + h * 64;
  const bf16* Vg = Vt + (size_t)(bh * 64) * 1024;

  // prologue: stage Q tile + K/V tile 0 (buffer 0)
#pragma unroll
  for (int cc = 0; cc < 2; ++cc) {
    int kc = w * 2 + cc;
    async_load16(Qg + (size_t)lane * 3072 + kc * 8,        &Qs[kc][0][0]);
    async_load16(Qg + (size_t)(64 + lane) * 3072 + kc * 8, &Qs[kc][64][0]);
  }
  {
    const bf16* Kg2 = Kg + (size_t)lane * 3072;
    const bf16* Vg2 = Vg + (size_t)lane * 1024;
    async_load16(Kg2 + (w * 2) * 8,     &Ks[0][w * 2][0][0]);
    async_load16(Kg2 + (w * 2 + 1) * 8, &Ks[0][w * 2 + 1][0][0]);
    async_load16(Vg2 + (w * 2) * 8,     &Vs[0][w * 2][0][0]);
    async_load16(Vg2 + (w * 2 + 1) * 8, &Vs[0][w * 2 + 1][0][0]);
  }
  __syncthreads();

  // hoist Q fragments (invariant over kv loop)
  bf16x8 qfr[2][2];
#pragma unroll
  for (int ks = 0; ks < 2; ++ks)
#pragma unroll
    for (int nt = 0; nt < 2; ++nt)
      qfr[ks][nt] = *(const bf16x8*)&Qs[ks * 4 + quad][w * 32 + nt * 16 + q15][0];

  floatx4 oacc[4][2];
  float l_i[2] = {0.f, 0.f};
#pragma unroll
  for (int nt = 0; nt < 2; ++nt)
#pragma unroll
    for (int mt = 0; mt < 4; ++mt) oacc[mt][nt] = (floatx4){0.f, 0.f, 0.f, 0.f};

  for (int kt = 0; kt < 16; ++kt) {
    int cur = kt & 1;
    __syncthreads();   // drains prefetch(kt); at kt=0 also fences Qs->PsB reuse
    if (kt + 1 < 16) {
      int kv0n = (kt + 1) * 64;
      const bf16* Kg3 = Kg + (size_t)(kv0n + lane) * 3072;
      const bf16* Vg3 = Vg + (size_t)lane * 1024 + kv0n;
      async_load16(Kg3 + (w * 2) * 8,     &Ks[cur ^ 1][w * 2][0][0]);
      async_load16(Kg3 + (w * 2 + 1) * 8, &Ks[cur ^ 1][w * 2 + 1][0][0]);
      async_load16(Vg3 + (w * 2) * 8,     &Vs[cur ^ 1][w * 2][0][0]);
      async_load16(Vg3 + (w * 2 + 1) * 8, &Vs[cur ^ 1][w * 2 + 1][0][0]);
    }

    // S^T = K Q^T
    floatx4 sacc[4][2];
#pragma unroll
    for (int mt = 0; mt < 4; ++mt)
#pragma unroll
      for (int nt = 0; nt < 2; ++nt) sacc[mt][nt] = (floatx4){0.f, 0.f, 0.f, 0.f};
#pragma unroll
    for (int ks = 0; ks < 2; ++ks) {
      bf16x8 kf[4];
#pragma unroll
      for (int mt = 0; mt < 4; ++mt)
        kf[mt] = *(const bf16x8*)&Ks[cur][ks * 4 + quad][mt * 16 + q15][0];
#pragma unroll
      for (int mt = 0; mt < 4; ++mt)
#pragma unroll
        for (int nt = 0; nt < 2; ++nt)
          sacc[mt][nt] = mfma16(kf[mt], qfr[ks][nt], sacc[mt][nt]);
    }

    // softmax numerator: p = exp2(s) (no max/rescale; logits bounded)
#pragma unroll
    for (int nt = 0; nt < 2; ++nt) {
      float rsum = 0.f;
#pragma unroll
      for (int mt = 0; mt < 4; ++mt)
#pragma unroll
        for (int r = 0; r < 4; ++r) {
          float p = fexp2(sacc[mt][nt][r]);
          sacc[mt][nt][r] = p;
          rsum += p;
        }
      rsum += __shfl_xor(rsum, 16);
      rsum += __shfl_xor(rsum, 32);
      l_i[nt] += rsum;
    }

    // P^T -> per-wave LDS region (B-frag layout), same-wave RAW via lgkmcnt
#pragma unroll
    for (int nt = 0; nt < 2; ++nt)
#pragma unroll
      for (int mt = 0; mt < 4; ++mt) {
        bf16x4 pk = {(__bf16)sacc[mt][nt][0], (__bf16)sacc[mt][nt][1],
                     (__bf16)sacc[mt][nt][2], (__bf16)sacc[mt][nt][3]};
        int kc = mt * 2 + (quad >> 1);
        *(bf16x4*)&PsB[(size_t)(w * 2 + nt) * 1024 + kc * 128 + q15 * 8 + (quad & 1) * 4] = pk;
      }

    // O^T += V^T P^T
#pragma unroll
    for (int ks = 0; ks < 2; ++ks) {
      bf16x8 vf[4], pf[2];
#pragma unroll
      for (int mt = 0; mt < 4; ++mt)
        vf[mt] = *(const bf16x8*)&Vs[cur][ks * 4 + quad][mt * 16 + q15][0];
#pragma unroll
      for (int nt = 0; nt < 2; ++nt)
        pf[nt] = *(const bf16x8*)&PsB[(size_t)(w * 2 + nt) * 1024 + (ks * 4 + quad) * 128 + q15 * 8];
#pragma unroll
      for (int mt = 0; mt < 4; ++mt)
#pragma unroll
        for (int nt = 0; nt < 2; ++nt) oacc[mt][nt] = mfma16(vf[mt], pf[nt], oacc[mt][nt]);
    }
  }

  __syncthreads();
  bf16* T = (bf16*)smem + w * 2304;   // [32 q][72]; overlaps dead Qs/PsB + Ks head
#pragma unroll
  for (int nt = 0; nt < 2; ++nt) {
    float inv = 1.f / l_i[nt];
#pragma unroll
    for (int mt = 0; mt < 4; ++mt) {
      bf16x4 pk = {(__bf16)(oacc[mt][nt][0] * inv), (__bf16)(oacc[mt][nt][1] * inv),
                   (__bf16)(oacc[mt][nt][2] * inv), (__bf16)(oacc[mt][nt][3] * inv)};
      *(bf16x4*)&T[(nt * 16 + q15) * 72 + mt * 16 + quad * 4] = pk;
    }
  }
  __syncthreads();
  int row = lane >> 1, ch = (lane & 1) * 32;
  const bf16* Tr = T + row * 72 + ch;
  bf16* outp = attn_out + (size_t)(b * 1024 + q0 + w * 32 + row) * 1024 + h * 64 + ch;
#pragma unroll
  for (int i = 0; i < 4; ++i) *(bf16x8*)&outp[i * 8] = *(const bf16x8*)&Tr[i * 8];
}

// ---------------------------------------------------------------------------
extern "C" void kernel_launch(void* const* d_in, const int* in_sizes, int n_in,
                              void* d_out, int out_size, void* d_ws, size_t ws_size,
                              hipStream_t stream) {
  (void)in_sizes; (void)n_in; (void)out_size; (void)ws_size;
  const float* x       = (const float*)d_in[0];   // 8x1024x1024
  const float* W_qkv   = (const float*)d_in[1];   // 3072x1024
  const float* W_proj  = (const float*)d_in[2];   // 1024x1024
  const float* b_proj  = (const float*)d_in[3];   // 1024
  const float* coef_k  = (const float*)d_in[4];   // 10x3000
  const float* coef_v  = (const float*)d_in[5];   // 10x3000
  const int*   indices = (const int*)d_in[6];     // 10x3000
  const int*   task    = (const int*)d_in[7];     // scalar

  // Workspace (106 MB peak). attn_out aliases the dead Sf/S2b/Tt region.
  char* w8 = (char*)d_ws;
  float* Sf     = (float*)(w8);                   // 8MB  (2 fp32 planes, transient)
  bf16*  S2b    = (bf16*) (w8 + (8u  << 20));     // 4MB  [2048][1024] (transient)
  bf16*  Tt     = (bf16*) (w8 + (12u << 20));     // 4MB  [2][1024][1024] (transient)
  bf16*  Bmtb   = (bf16*) (w8 + (16u << 20));     // 2MB
  bf16*  Wcb    = (bf16*) (w8 + (18u << 20));     // 6MB  [3072][1024]
  bf16*  xb     = (bf16*) (w8 + (24u << 20));     // 16MB
  bf16*  qkvb   = (bf16*) (w8 + (40u << 20));     // 48MB [8192][3072]
  bf16*  Vt     = (bf16*) (w8 + (88u << 20));     // 16MB [128][64][1024]
  bf16*  Wprojb = (bf16*) (w8 + (104u << 20));    // 2MB
  bf16*  attnout= (bf16*) (w8);                   // 16MB alias (Sf/S2b/Tt dead)

  // Dense S scatter (fp32 planes), then ONE merged prep launch
  hipMemsetAsync(Sf, 0, (size_t)8 << 20, stream);
  scatter_s<<<118, 256, 0, stream>>>(coef_k, coef_v, indices, task, Sf);
  prep_kernel<<<13312, 256, 0, stream>>>(W_qkv, W_proj, x, Sf,
                                         Bmtb, Wcb, Wprojb, xb, S2b);

  // LoRA: T = S @ Bm (stored transposed per plane), then both band GEMMs
  // W_band = Bm^T @ T_plane + W_qkv_band fused into one launch via grid.z.
  // 64-tile GEMM: 512 blocks each (vs 128) -> 2 blocks/CU instead of 0.5.
  gemm64_bf16_nt<<<dim3(16, 32), 256, 0, stream>>>(S2b, Bmtb, nullptr, nullptr,
                                                   nullptr, nullptr, Tt, 0, 1024);
  gemm64_bf16_nt<<<dim3(16, 16, 2), 256, 0, stream>>>(Bmtb, Tt, Wcb + (1u << 20), nullptr,
                                                      W_qkv + (1u << 20), nullptr, nullptr,
                                                      1 << 30, 1024);

  // qkv = xb @ Wcb^T -> q,k bands bf16 into qkvb; v band transposed into Vt
  // (128-tile kernel: 64-tiles would double its LDS traffic per FLOP)
  gemm_bf16_nt<<<dim3(24, 64), 256, 0, stream>>>(xb, Wcb, qkvb, nullptr,
                                                 nullptr, nullptr, Vt, 2048, 3072);

  // attention
  attn_mfma<<<dim3(8, 128), 256, 0, stream>>>(qkvb, Vt, attnout);

  // out = attn_out @ W_proj^T + b_proj  (fp32 out)
  // 64-tile GEMM: 2048 blocks -> 8 blocks/CU (vs 2 with 128-tiles)
  gemm64_bf16_nt<<<dim3(16, 128), 256, 0, stream>>>(attnout, Wprojb, nullptr, (float*)d_out,
                                                    nullptr, b_proj, nullptr, 1 << 30, 1024);
}